// Round 8
// baseline (3113.158 us; speedup 1.0000x reference)
//
#include <hip/hip_runtime.h>
#include <hip/hip_bf16.h>
#include <math.h>

typedef __hip_bfloat16 bf16;
__device__ __forceinline__ float b2f(bf16 x) { return __bfloat162float(x); }

#define LN_EPS 1e-12f
#define NEG_INF (-3.0e38f)

__global__ __launch_bounds__(256)
void zero_kernel(int* __restrict__ p, int n)
{
    int i = blockIdx.x * 256 + threadIdx.x;
    if (i < n) p[i] = 0;
}

__global__ __launch_bounds__(256)
void copy_int_kernel(const int* __restrict__ src, int* __restrict__ dst, int n)
{
    int i = blockIdx.x * 256 + threadIdx.x;
    if (i < n) dst[i] = src[i];
}

// ============================ LayerNorm (f32 -> f32, f64 stats) ============================
__global__ __launch_bounds__(256)
void ln_kernel(const float* __restrict__ in, const float* __restrict__ g,
               const float* __restrict__ b, float* __restrict__ out)
{
    const int D = 1024;
    int row = blockIdx.x, tid = threadIdx.x;
    size_t base = (size_t)row * D + tid * 4;
    float x[4];
    #pragma unroll
    for (int i = 0; i < 4; ++i) x[i] = in[base + i];
    double s  = (double)x[0] + x[1] + x[2] + x[3];
    double sq = (double)x[0]*x[0] + (double)x[1]*x[1] + (double)x[2]*x[2] + (double)x[3]*x[3];
    __shared__ double rs[256], rq[256];
    rs[tid] = s; rq[tid] = sq;
    __syncthreads();
    for (int o = 128; o > 0; o >>= 1) {
        if (tid < o) { rs[tid] += rs[tid + o]; rq[tid] += rq[tid + o]; }
        __syncthreads();
    }
    double mean = rs[0] * (1.0 / D);
    double var  = rq[0] * (1.0 / D) - mean * mean;
    double inv  = rsqrt(var + (double)LN_EPS);
    #pragma unroll
    for (int i = 0; i < 4; ++i) {
        int col = tid * 4 + i;
        out[base + i] = (float)(((double)x[i] - mean) * inv * (double)g[col] + (double)b[col]);
    }
}

// ============================ generic NT GEMM (f32 storage, templated accumulator) =========
// C[m,n] = sum_k A[m,k]*B[row(n),k] (+bias[row(n)]) (+residual[m,n])
// mode 0: out[m*ldc+n]  mode 1: out[(n>>6)*M*64 + m*64 + (n&63)]  mode 3: out[(n>>3)*M*8 + m*8 + (n&7)]
#define BM 64
#define BN 64
#define BK 16
template<typename ACC>
__global__ __launch_bounds__(256)
void gemm_nt_t(const float* __restrict__ A, int lda,
               const float* __restrict__ B, int ldb,
               const int* __restrict__ gatherB,
               const float* __restrict__ bias,
               const float* __restrict__ residual,
               void* __restrict__ out_, int oBf, int ldc, int mode,
               int M, int N, int Kd)
{
    __shared__ float As[BK][BM + 1];
    __shared__ float Bs[BK][BN + 1];
    int tid = threadIdx.x;
    int bm = blockIdx.y * BM, bn = blockIdx.x * BN;
    int lm  = tid >> 2;
    int lk4 = (tid & 3) * 4;
    int tm = (tid >> 4) * 4, tn = (tid & 15) * 4;
    ACC acc[4][4] = {};
    for (int k0 = 0; k0 < Kd; k0 += BK) {
        {
            const float* p = A + (size_t)(bm + lm) * lda + k0 + lk4;
            #pragma unroll
            for (int i = 0; i < 4; ++i) As[lk4 + i][lm] = p[i];
        }
        {
            int r = bn + lm;
            if (gatherB) r = gatherB[r] & 4095;
            const float* p = B + (size_t)r * ldb + k0 + lk4;
            #pragma unroll
            for (int i = 0; i < 4; ++i) Bs[lk4 + i][lm] = p[i];
        }
        __syncthreads();
        #pragma unroll
        for (int k = 0; k < BK; ++k) {
            float av[4], bw[4];
            #pragma unroll
            for (int i = 0; i < 4; ++i) av[i] = As[k][tm + i];
            #pragma unroll
            for (int j = 0; j < 4; ++j) bw[j] = Bs[k][tn + j];
            #pragma unroll
            for (int i = 0; i < 4; ++i)
                #pragma unroll
                for (int j = 0; j < 4; ++j)
                    acc[i][j] += (ACC)av[i] * (ACC)bw[j];
        }
        __syncthreads();
    }
    #pragma unroll
    for (int i = 0; i < 4; ++i) {
        int m = bm + tm + i;
        #pragma unroll
        for (int j = 0; j < 4; ++j) {
            int n = bn + tn + j;
            ACC v = acc[i][j];
            if (bias) { int bi2 = gatherB ? (gatherB[n] & 4095) : n; v += (ACC)bias[bi2]; }
            if (residual) v += (ACC)residual[(size_t)m * ldc + n];
            size_t idx;
            if (mode == 0)      idx = (size_t)m * ldc + n;
            else if (mode == 1) idx = (size_t)(n >> 6) * ((size_t)M * 64) + (size_t)m * 64 + (n & 63);
            else                idx = (size_t)(n >> 3) * ((size_t)M * 8) + (size_t)m * 8 + (n & 7);
            if (oBf) ((bf16*)out_)[idx] = __float2bfloat16((float)v);
            else     ((float*)out_)[idx] = (float)v;
        }
    }
}

// ==== NN GEMM: gelu(logits bf16) @ W2[sids] + b2 + attnO(f32) -> d_out f32 at offset ====
__global__ __launch_bounds__(256)
void gemm_nn_out(const bf16* __restrict__ A, const float* __restrict__ B,
                 const int* __restrict__ gk, const float* __restrict__ bias,
                 const float* __restrict__ residual, float* __restrict__ out,
                 size_t outOff)
{
    const int lda = 1024, ldb = 1024, ldc = 1024, Kd = 1024;
    __shared__ float As[BK][BM + 1];
    __shared__ float Bs[BK][BN + 1];
    int tid = threadIdx.x;
    int bm = blockIdx.y * BM, bn = blockIdx.x * BN;
    int lm  = tid >> 2;
    int lk4 = (tid & 3) * 4;
    int bkr = tid >> 4;
    int bn4 = (tid & 15) * 4;
    int tm = (tid >> 4) * 4, tn = (tid & 15) * 4;
    float acc[4][4] = {};
    for (int k0 = 0; k0 < Kd; k0 += BK) {
        {
            const bf16* p = A + (size_t)(bm + lm) * lda + k0 + lk4;
            #pragma unroll
            for (int i = 0; i < 4; ++i) {
                float x = b2f(p[i]);
                As[lk4 + i][lm] = 0.5f * x * (1.0f + erff(x * 0.70710678118654752f));
            }
        }
        {
            int r = gk[k0 + bkr] & 4095;
            const float* q = B + (size_t)r * ldb + bn + bn4;
            #pragma unroll
            for (int i = 0; i < 4; ++i) Bs[bkr][bn4 + i] = q[i];
        }
        __syncthreads();
        #pragma unroll
        for (int k = 0; k < BK; ++k) {
            float av[4], bw[4];
            #pragma unroll
            for (int i = 0; i < 4; ++i) av[i] = As[k][tm + i];
            #pragma unroll
            for (int j = 0; j < 4; ++j) bw[j] = Bs[k][tn + j];
            #pragma unroll
            for (int i = 0; i < 4; ++i)
                #pragma unroll
                for (int j = 0; j < 4; ++j)
                    acc[i][j] += av[i] * bw[j];
        }
        __syncthreads();
    }
    #pragma unroll
    for (int i = 0; i < 4; ++i) {
        int m = bm + tm + i;
        #pragma unroll
        for (int j = 0; j < 4; ++j) {
            int n = bn + tn + j;
            float v = acc[i][j] + bias[n] + residual[(size_t)m * ldc + n];
            out[outOff + (size_t)m * ldc + n] = v;
        }
    }
}

// ============================ flash attention (all f32 storage, f64 accumulation) ==========
// q,k,v: head-blocked f32 [hl][2048][64]. ctx -> d_out row-major f32. LDS ~52.7KB.
__global__ __launch_bounds__(256)
void flash_kernel(const float* __restrict__ q, const float* __restrict__ k,
                  const float* __restrict__ v, const float* __restrict__ amask,
                  float* __restrict__ ctx, int hbase)
{
    int qt = blockIdx.x, hl = blockIdx.y, tid = threadIdx.x;
    int ty = tid >> 4, tx = tid & 15;
    __shared__ __align__(16) float Qs[64][68];
    __shared__ __align__(16) float KVs[64][68];   // K during score phase, V during PV phase
    __shared__ float St[64][66];
    __shared__ float mrow[64], arow[64], msk[64];
    __shared__ double lrow[64];
    const float* qh = q + (size_t)hl * 131072 + (size_t)qt * 4096;
    #pragma unroll
    for (int rep = 0; rep < 4; ++rep) {
        int lin = rep * 1024 + tid * 4;
        int r = lin >> 6, c = lin & 63;
        float4 u = *(const float4*)(qh + r * 64 + c);
        Qs[r][c] = u.x; Qs[r][c+1] = u.y; Qs[r][c+2] = u.z; Qs[r][c+3] = u.w;
    }
    if (tid < 64) { mrow[tid] = NEG_INF; lrow[tid] = 0.0; }
    double o[4][4] = {};
    for (int kt = 0; kt < 32; ++kt) {
        const float* kh = k + (size_t)hl * 131072 + (size_t)kt * 4096;
        const float* vh = v + (size_t)hl * 131072 + (size_t)kt * 4096;
        #pragma unroll
        for (int rep = 0; rep < 4; ++rep) {
            int lin = rep * 1024 + tid * 4;
            int r = lin >> 6, c = lin & 63;
            float4 u = *(const float4*)(kh + r * 64 + c);
            KVs[r][c] = u.x; KVs[r][c+1] = u.y; KVs[r][c+2] = u.z; KVs[r][c+3] = u.w;
        }
        if (tid < 64) msk[tid] = 1000.0f * (1.0f - amask[kt * 64 + tid]);
        __syncthreads();
        // S = (Q K^T)/8 - mask   (f64 acc)
        double sc4[4][4] = {};
        #pragma unroll 4
        for (int d = 0; d < 64; d += 4) {
            float4 qv[4], kv[4];
            #pragma unroll
            for (int i = 0; i < 4; ++i) qv[i] = *(const float4*)&Qs[ty * 4 + i][d];
            #pragma unroll
            for (int j = 0; j < 4; ++j) kv[j] = *(const float4*)&KVs[tx * 4 + j][d];
            #pragma unroll
            for (int i = 0; i < 4; ++i)
                #pragma unroll
                for (int j = 0; j < 4; ++j)
                    sc4[i][j] += (double)qv[i].x * kv[j].x + (double)qv[i].y * kv[j].y
                               + (double)qv[i].z * kv[j].z + (double)qv[i].w * kv[j].w;
        }
        __syncthreads();   // K reads done; KVs reusable for V
        #pragma unroll
        for (int i = 0; i < 4; ++i)
            #pragma unroll
            for (int j = 0; j < 4; ++j)
                St[ty * 4 + i][tx * 4 + j] = (float)(sc4[i][j] * 0.125) - msk[tx * 4 + j];
        // load V into KVs (overlaps St write; both complete at next barrier)
        #pragma unroll
        for (int rep = 0; rep < 4; ++rep) {
            int lin = rep * 1024 + tid * 4;
            int r = lin >> 6, c = lin & 63;
            float4 w = *(const float4*)(vh + r * 64 + c);
            KVs[r][c] = w.x; KVs[r][c+1] = w.y; KVs[r][c+2] = w.z; KVs[r][c+3] = w.w;
        }
        __syncthreads();
        // online softmax row update
        if (tid < 64) {
            float mo = mrow[tid], mx = mo;
            #pragma unroll 8
            for (int j = 0; j < 64; ++j) mx = fmaxf(mx, St[tid][j]);
            float al = expf(mo - mx);
            double sum = 0.0;
            #pragma unroll 8
            for (int j = 0; j < 64; ++j) { float p = expf(St[tid][j] - mx); St[tid][j] = p; sum += p; }
            lrow[tid] = lrow[tid] * al + sum;
            mrow[tid] = mx;
            arow[tid] = al;
        }
        __syncthreads();
        // O = O*alpha + P V   (f64 acc)
        #pragma unroll
        for (int i = 0; i < 4; ++i) {
            double al = arow[ty * 4 + i];
            #pragma unroll
            for (int j = 0; j < 4; ++j) o[i][j] *= al;
        }
        for (int j2 = 0; j2 < 64; ++j2) {
            float4 vv = *(const float4*)&KVs[j2][tx * 4];
            #pragma unroll
            for (int i = 0; i < 4; ++i) {
                double p = St[ty * 4 + i][j2];
                o[i][0] += p * vv.x; o[i][1] += p * vv.y; o[i][2] += p * vv.z; o[i][3] += p * vv.w;
            }
        }
        __syncthreads();
    }
    #pragma unroll
    for (int i = 0; i < 4; ++i) {
        int row = ty * 4 + i;
        double inv = 1.0 / lrow[row];
        size_t base = (size_t)(qt * 64 + row) * 1024 + (hbase + hl) * 64 + tx * 4;
        #pragma unroll
        for (int j = 0; j < 4; ++j)
            ctx[base + j] = (float)(o[i][j] * inv);
    }
}

// ============================ hashing / routing ============================
__global__ __launch_bounds__(256)
void code_n_kernel(const float* __restrict__ projn, int* __restrict__ code_n)
{
    int i = blockIdx.x * 256 + threadIdx.x;       // 65536 = L*NC ; projn [l][n][8]
    const float* p = projn + (size_t)i * 8;
    int code = 0;
    #pragma unroll
    for (int k = 0; k < 8; ++k) code |= ((int)(p[k] > 0.0f)) << k;
    code_n[i] = code;
}

__global__ __launch_bounds__(256)
void code_t_kernel(float* __restrict__ pt, int* __restrict__ code_t)
{
    int i = blockIdx.x * 256 + threadIdx.x;       // 32768 = 2048*16
    int t = i >> 4, l = i & 15;
    float* p = pt + (size_t)t * 128 + l * 8;
    int code = 0;
    #pragma unroll
    for (int k = 0; k < 8; ++k) {
        float v = p[k];
        code |= ((int)(v > 0.0f)) << k;
        p[k] = tanhf(v);                           // in-place tanh for agree
    }
    code_t[l * 2048 + t] = code;
}

__global__ __launch_bounds__(256)
void hist_kernel(const int* __restrict__ code_t, int* __restrict__ hist)
{
    int i = blockIdx.x * 256 + threadIdx.x;       // 32768 = 2*16*1024
    int c = i >> 14, l = (i >> 10) & 15, t = i & 1023;
    int code = code_t[l * 2048 + c * 1024 + t] & 255;
    atomicAdd(&hist[(c * 16 + l) * 256 + code], 1);
}

__global__ __launch_bounds__(256)
void score_kernel(const int* __restrict__ hist, const int* __restrict__ code_n,
                  int* __restrict__ score, int* __restrict__ shist)
{
    int i = blockIdx.x * 256 + threadIdx.x;       // 8192 = 2*4096
    int c = i >> 12, n = i & 4095;
    int s = 0;
    #pragma unroll
    for (int l = 0; l < 16; ++l) s += hist[(c * 16 + l) * 256 + (code_n[l * 4096 + n] & 255)];
    if (s < 0) s = 0; if (s > 16384) s = 16384;
    score[c * 4096 + n] = s;
    atomicAdd(&shist[c * 16385 + s], 1);
}

__global__ __launch_bounds__(256)
void select_kernel(const int* __restrict__ shist, int* __restrict__ selmeta)
{
    int c = blockIdx.x, tid = threadIdx.x;
    const int* bins = shist + c * 16385;
    __shared__ int psum[256];
    int s = 0;
    for (int i = 0; i < 64; ++i) s += bins[tid * 64 + i];
    if (tid == 255) s += bins[16384];
    psum[tid] = s;
    __syncthreads();
    if (tid == 0) {
        int cum = 0, sstar = 0, cntge = 0;
        for (int t = 255; t >= 0; --t) {
            if (cum + psum[t] >= 1024) {
                int hi = (t == 255) ? 16384 : t * 64 + 63;
                for (int b = hi; b >= t * 64; --b) {
                    cum += bins[b];
                    if (cum >= 1024) { sstar = b; cntge = cum; break; }
                }
                break;
            }
            cum += psum[t];
        }
        selmeta[c * 2]     = sstar;
        selmeta[c * 2 + 1] = 1024 - (cntge - bins[sstar]);
    }
}

__global__ __launch_bounds__(256)
void build_sids_kernel(const int* __restrict__ score, const int* __restrict__ selmeta,
                       int* __restrict__ sids)
{
    int c = blockIdx.x, tid = threadIdx.x;
    const int* sc2 = score + c * 4096;
    int sstar = selmeta[c * 2], need_eq = selmeta[c * 2 + 1];
    __shared__ int scan[256];
    int base = tid * 16;
    int mysc[16];
    int eqc = 0;
    #pragma unroll
    for (int i = 0; i < 16; ++i) { mysc[i] = sc2[base + i]; eqc += (mysc[i] == sstar); }
    scan[tid] = eqc; __syncthreads();
    for (int o = 1; o < 256; o <<= 1) {
        int v = (tid >= o) ? scan[tid - o] : 0;
        __syncthreads();
        scan[tid] += v;
        __syncthreads();
    }
    int eqr = scan[tid] - eqc;
    __syncthreads();
    int selc = 0; unsigned flags = 0;
    #pragma unroll
    for (int i = 0; i < 16; ++i) {
        bool sel = false;
        if (mysc[i] > sstar) sel = true;
        else if (mysc[i] == sstar) { sel = (eqr < need_eq); eqr++; }
        if (sel) { flags |= (1u << i); selc++; }
    }
    scan[tid] = selc; __syncthreads();
    for (int o = 1; o < 256; o <<= 1) {
        int v = (tid >= o) ? scan[tid - o] : 0;
        __syncthreads();
        scan[tid] += v;
        __syncthreads();
    }
    int pos = scan[tid] - selc;
    #pragma unroll
    for (int i = 0; i < 16; ++i)
        if (flags & (1u << i)) { if (pos < 1024) sids[c * 1024 + pos] = base + i; pos++; }
}

__global__ __launch_bounds__(256)
void tanhpn_kernel(const float* __restrict__ projn, const int* __restrict__ sids,
                   float* __restrict__ tanhpn)
{
    int i = blockIdx.x * 256 + threadIdx.x;       // 262144 = 2*1024*128
    int c = i >> 17;
    int r = i & 131071;
    int s = r >> 7, j = r & 127;
    int l = j >> 3, k = j & 7;
    int n = sids[c * 1024 + s] & 4095;
    tanhpn[(size_t)c * 131072 + (size_t)s * 128 + j] = tanhf(projn[(size_t)l * 32768 + (size_t)n * 8 + k]);
}

// ============================ per-row top-64 pos/neg + triplet ============================
__global__ __launch_bounds__(256)
void topk_kernel(const bf16* __restrict__ logits, const float* __restrict__ tanhpt,
                 const float* __restrict__ tanhpn, float* __restrict__ trip)
{
    int t = blockIdx.x;
    int c = t >> 10, tid = threadIdx.x;
    __shared__ float vals[1024];
    __shared__ float agr[1024];
    __shared__ float qrow[128];
    __shared__ float rv[256];
    __shared__ int   ri[256];
    __shared__ float msum[2];
    if (tid < 128) qrow[tid] = tanhpt[(size_t)t * 128 + tid];
    __syncthreads();
    for (int s = tid; s < 1024; s += 256) {
        const float* pn = tanhpn + ((size_t)c * 1024 + s) * 128;
        float acc = 0.0f;
        #pragma unroll 8
        for (int d = 0; d < 128; ++d) acc += qrow[d] * pn[d];
        agr[s] = acc * (1.0f / 128.0f);
    }
    const bf16* lrow = logits + (size_t)t * 1024;
    for (int p = 0; p < 2; ++p) {
        for (int i = tid; i < 1024; i += 256) { float v = b2f(lrow[i]); vals[i] = p ? -v : v; }
        __syncthreads();
        float asum = 0.0f;
        for (int it = 0; it < 64; ++it) {
            float bv = NEG_INF; int bi = 1 << 30;
            for (int i = tid; i < 1024; i += 256) {
                float v = vals[i];
                if (v > bv) { bv = v; bi = i; }
            }
            rv[tid] = bv; ri[tid] = bi;
            __syncthreads();
            for (int o = 128; o > 0; o >>= 1) {
                if (tid < o) {
                    float v = rv[tid + o]; int j = ri[tid + o];
                    if (v > rv[tid] || (v == rv[tid] && j < ri[tid])) { rv[tid] = v; ri[tid] = j; }
                }
                __syncthreads();
            }
            int w = ri[0] & 1023;
            if (tid == 0) { asum += agr[w]; vals[w] = NEG_INF; }
            __syncthreads();
        }
        if (tid == 0) msum[p] = asum * (1.0f / 64.0f);
        __syncthreads();
    }
    if (tid == 0) {
        float v = msum[1] - msum[0] + 0.5f;
        trip[t] = v > 0.0f ? v : 0.0f;
    }
}

__global__ __launch_bounds__(256)
void trip_mean_kernel(const float* __restrict__ trip, float* __restrict__ out)
{
    int tid = threadIdx.x;
    float s = 0.0f;
    for (int i = tid; i < 2048; i += 256) s += trip[i];
    __shared__ float rs[256];
    rs[tid] = s; __syncthreads();
    for (int o = 128; o > 0; o >>= 1) { if (tid < o) rs[tid] += rs[tid + o]; __syncthreads(); }
    if (tid == 0) out[2097152] = rs[0] * (1.0f / 2048.0f);
}

// ============================ launch ============================
extern "C" void kernel_launch(void* const* d_in, const int* in_sizes, int n_in,
                              void* d_out, int out_size, void* d_ws, size_t ws_size,
                              hipStream_t stream)
{
    const float* hidden = (const float*)d_in[0];
    const float* amask  = (const float*)d_in[1];
    const float* ln1g   = (const float*)d_in[2];
    const float* ln1b   = (const float*)d_in[3];
    const float* Wq     = (const float*)d_in[4];
    const float* bq     = (const float*)d_in[5];
    const float* Wk     = (const float*)d_in[6];
    const float* bk     = (const float*)d_in[7];
    const float* Wv     = (const float*)d_in[8];
    const float* bv     = (const float*)d_in[9];
    const float* Wo     = (const float*)d_in[10];
    const float* bo     = (const float*)d_in[11];
    const float* ln2g   = (const float*)d_in[12];
    const float* ln2b   = (const float*)d_in[13];
    const float* W1     = (const float*)d_in[14];
    const float* b1     = (const float*)d_in[15];
    const float* Whash  = (const float*)d_in[16];
    const float* W2     = (const float*)d_in[17];
    const float* b2w    = (const float*)d_in[18];
    float* out = (float*)d_out;
    float* ws  = (float*)d_ws;
    const size_t MB = 1024 * 1024;
    if (ws_size < 20 * MB) return;

    // ---- ws layout (floats), 20 MB ----
    float* xln    = ws;                 // [0,8MB)   2048x1024, dead after last QKV proj
    float* qg     = ws + 2097152;       // [8,12MB)  8 heads [hl][2048][64]
    float* kg     = ws + 3145728;       // [12,16MB)
    float* vg     = ws + 4194304;       // [16,20MB)
    float* attnO  = ws + 2097152;       // [8,16MB)  after flash (qg/kg dead); live to end
    float* normed = ws;                 // [0,8MB)   over xln
    bf16*  logits = (bf16*)(ws + 4194304); // [16,20MB) over vg, bf16 2048x1024
    int*   sids_ws = (int*)ws;          // [0,8KB)   after normed dead

    // ---- d_out scratch layout (floats) ----
    float* ctx    = out;                // [0,8MB) during attention
    float* projn  = out;                // [0,2MB)  [l][n][8] after O-proj
    float* tanhpt = out + 524288;       // [2,3MB)  2048x128
    float* tanhpn = out + 786432;       // [3,4MB)  2x1024x128
    int*   dints  = (int*)out + 1048576;// [4MB...)
    int*   code_n = dints;              // 65536
    int*   code_t = dints + 65536;      // 32768
    int*   hist   = dints + 98304;      // 8192
    int*   score  = dints + 106496;     // 8192
    int*   shist  = dints + 114688;     // 32772
    int*   selmeta= dints + 147460;     // 4
    int*   sids   = dints + 147464;     // 2048
    float* trip   = (float*)(dints + 149512); // 2048

    // ---- attention (2 head-groups of 8; f64 accumulation throughout) ----
    ln_kernel<<<2048, 256, 0, stream>>>(hidden, ln1g, ln1b, xln);
    for (int g = 0; g < 2; ++g) {
        const size_t wOff = (size_t)g * 512 * 1024;
        gemm_nt_t<double><<<dim3(8, 32), 256, 0, stream>>>(xln, 1024, Wq + wOff, 1024, nullptr, bq + g * 512, nullptr, qg, 0, 1024, 1, 2048, 512, 1024);
        gemm_nt_t<double><<<dim3(8, 32), 256, 0, stream>>>(xln, 1024, Wk + wOff, 1024, nullptr, bk + g * 512, nullptr, kg, 0, 1024, 1, 2048, 512, 1024);
        gemm_nt_t<double><<<dim3(8, 32), 256, 0, stream>>>(xln, 1024, Wv + wOff, 1024, nullptr, bv + g * 512, nullptr, vg, 0, 1024, 1, 2048, 512, 1024);
        flash_kernel<<<dim3(32, 8), 256, 0, stream>>>(qg, kg, vg, amask, ctx, g * 8);
    }
    // O-proj: attnO = ctx @ Wo^T + bo + hidden  -> ws[8,16MB)
    gemm_nt_t<double><<<dim3(16, 32), 256, 0, stream>>>(ctx, 1024, Wo, 1024, nullptr, bo, hidden, attnO, 0, 1024, 0, 2048, 1024, 1024);

    // ---- FFN routing (d_out free for scratch now) ----
    ln_kernel<<<2048, 256, 0, stream>>>(attnO, ln2g, ln2b, normed);
    gemm_nt_t<double><<<dim3(2, 64), 256, 0, stream>>>(W1, 1024, Whash, 1024, nullptr, nullptr, nullptr, projn, 0, 0, 3, 4096, 128, 1024);
    code_n_kernel<<<256, 256, 0, stream>>>(projn, code_n);
    gemm_nt_t<double><<<dim3(2, 32), 256, 0, stream>>>(normed, 1024, Whash, 1024, nullptr, nullptr, nullptr, tanhpt, 0, 128, 0, 2048, 128, 1024);
    zero_kernel<<<193, 256, 0, stream>>>(hist, 49156);   // hist + score + shist
    code_t_kernel<<<128, 256, 0, stream>>>(tanhpt, code_t);
    hist_kernel<<<128, 256, 0, stream>>>(code_t, hist);
    score_kernel<<<32, 256, 0, stream>>>(hist, code_n, score, shist);
    select_kernel<<<2, 256, 0, stream>>>(shist, selmeta);
    build_sids_kernel<<<2, 256, 0, stream>>>(score, selmeta, sids);
    tanhpn_kernel<<<1024, 256, 0, stream>>>(projn, sids, tanhpn);

    // ---- logits (bf16, ws; f32 acc) ----
    for (int c = 0; c < 2; ++c)
        gemm_nt_t<float><<<dim3(16, 16), 256, 0, stream>>>(normed + (size_t)c * 1048576, 1024, W1, 1024,
                                                           sids + c * 1024, b1, nullptr,
                                                           logits + (size_t)c * 1048576, 1, 1024, 0, 1024, 1024, 1024);

    // ---- triplet (reads d_out scratch; must precede final writes) ----
    topk_kernel<<<2048, 256, 0, stream>>>(logits, tanhpt, tanhpn, trip);
    trip_mean_kernel<<<1, 256, 0, stream>>>(trip, out);

    // ---- final FFN output (overwrites d_out matrix) ----
    copy_int_kernel<<<8, 256, 0, stream>>>(sids, sids_ws, 2048);   // normed dead; sids out of d_out
    for (int c = 0; c < 2; ++c)
        gemm_nn_out<<<dim3(16, 16), 256, 0, stream>>>(logits + (size_t)c * 1048576, W2, sids_ws + c * 1024,
                                                      b2w, attnO + (size_t)c * 1048576,
                                                      out, (size_t)c * 1048576);
}

// Round 9
// 2233.716 us; speedup vs baseline: 1.3937x; 1.3937x over previous
//
#include <hip/hip_runtime.h>
#include <hip/hip_bf16.h>
#include <math.h>

typedef __hip_bfloat16 bf16;
__device__ __forceinline__ float b2f(bf16 x) { return __bfloat162float(x); }

#define LN_EPS 1e-12f
#define NEG_INF (-3.0e38f)

__global__ __launch_bounds__(256)
void zero_kernel(int* __restrict__ p, int n)
{
    int i = blockIdx.x * 256 + threadIdx.x;
    if (i < n) p[i] = 0;
}

__global__ __launch_bounds__(256)
void copy_int_kernel(const int* __restrict__ src, int* __restrict__ dst, int n)
{
    int i = blockIdx.x * 256 + threadIdx.x;
    if (i < n) dst[i] = src[i];
}

// ============================ LayerNorm (f32 -> f32, f64 stats) ============================
__global__ __launch_bounds__(256)
void ln_kernel(const float* __restrict__ in, const float* __restrict__ g,
               const float* __restrict__ b, float* __restrict__ out)
{
    const int D = 1024;
    int row = blockIdx.x, tid = threadIdx.x;
    size_t base = (size_t)row * D + tid * 4;
    float x[4];
    #pragma unroll
    for (int i = 0; i < 4; ++i) x[i] = in[base + i];
    double s  = (double)x[0] + x[1] + x[2] + x[3];
    double sq = (double)x[0]*x[0] + (double)x[1]*x[1] + (double)x[2]*x[2] + (double)x[3]*x[3];
    __shared__ double rs[256], rq[256];
    rs[tid] = s; rq[tid] = sq;
    __syncthreads();
    for (int o = 128; o > 0; o >>= 1) {
        if (tid < o) { rs[tid] += rs[tid + o]; rq[tid] += rq[tid + o]; }
        __syncthreads();
    }
    double mean = rs[0] * (1.0 / D);
    double var  = rq[0] * (1.0 / D) - mean * mean;
    double inv  = rsqrt(var + (double)LN_EPS);
    #pragma unroll
    for (int i = 0; i < 4; ++i) {
        int col = tid * 4 + i;
        out[base + i] = (float)(((double)x[i] - mean) * inv * (double)g[col] + (double)b[col]);
    }
}

// ============================ generic NT GEMM (f32 storage, templated accumulator) =========
#define BM 64
#define BN 64
#define BK 16
template<typename ACC>
__global__ __launch_bounds__(256)
void gemm_nt_t(const float* __restrict__ A, int lda,
               const float* __restrict__ B, int ldb,
               const int* __restrict__ gatherB,
               const float* __restrict__ bias,
               const float* __restrict__ residual,
               void* __restrict__ out_, int oBf, int ldc, int mode,
               int M, int N, int Kd)
{
    __shared__ float As[BK][BM + 1];
    __shared__ float Bs[BK][BN + 1];
    int tid = threadIdx.x;
    int bm = blockIdx.y * BM, bn = blockIdx.x * BN;
    int lm  = tid >> 2;
    int lk4 = (tid & 3) * 4;
    int tm = (tid >> 4) * 4, tn = (tid & 15) * 4;
    ACC acc[4][4] = {};
    for (int k0 = 0; k0 < Kd; k0 += BK) {
        {
            const float* p = A + (size_t)(bm + lm) * lda + k0 + lk4;
            #pragma unroll
            for (int i = 0; i < 4; ++i) As[lk4 + i][lm] = p[i];
        }
        {
            int r = bn + lm;
            if (gatherB) r = gatherB[r] & 4095;
            const float* p = B + (size_t)r * ldb + k0 + lk4;
            #pragma unroll
            for (int i = 0; i < 4; ++i) Bs[lk4 + i][lm] = p[i];
        }
        __syncthreads();
        #pragma unroll
        for (int k = 0; k < BK; ++k) {
            float av[4], bw[4];
            #pragma unroll
            for (int i = 0; i < 4; ++i) av[i] = As[k][tm + i];
            #pragma unroll
            for (int j = 0; j < 4; ++j) bw[j] = Bs[k][tn + j];
            #pragma unroll
            for (int i = 0; i < 4; ++i)
                #pragma unroll
                for (int j = 0; j < 4; ++j)
                    acc[i][j] += (ACC)av[i] * (ACC)bw[j];
        }
        __syncthreads();
    }
    #pragma unroll
    for (int i = 0; i < 4; ++i) {
        int m = bm + tm + i;
        #pragma unroll
        for (int j = 0; j < 4; ++j) {
            int n = bn + tn + j;
            ACC v = acc[i][j];
            if (bias) { int bi2 = gatherB ? (gatherB[n] & 4095) : n; v += (ACC)bias[bi2]; }
            if (residual) v += (ACC)residual[(size_t)m * ldc + n];
            size_t idx;
            if (mode == 0)      idx = (size_t)m * ldc + n;
            else if (mode == 1) idx = (size_t)(n >> 6) * ((size_t)M * 64) + (size_t)m * 64 + (n & 63);
            else                idx = (size_t)(n >> 3) * ((size_t)M * 8) + (size_t)m * 8 + (n & 7);
            if (oBf) ((bf16*)out_)[idx] = __float2bfloat16((float)v);
            else     ((float*)out_)[idx] = (float)v;
        }
    }
}

// ============================ QKV fused (z selects Q/K/V), f64 acc, mode1 out ==============
__global__ __launch_bounds__(256)
void qkv_kernel(const float* __restrict__ A,
                const float* __restrict__ Wq, const float* __restrict__ Wk, const float* __restrict__ Wv,
                const float* __restrict__ bq, const float* __restrict__ bk, const float* __restrict__ bv,
                float* __restrict__ qo, float* __restrict__ ko, float* __restrict__ vo)
{
    const int lda = 1024, ldb = 1024, Kd = 1024, M = 2048;
    const float* B    = (blockIdx.z == 0) ? Wq : (blockIdx.z == 1) ? Wk : Wv;
    const float* bias = (blockIdx.z == 0) ? bq : (blockIdx.z == 1) ? bk : bv;
    float* out        = (blockIdx.z == 0) ? qo : (blockIdx.z == 1) ? ko : vo;
    __shared__ float As[BK][BM + 1];
    __shared__ float Bs[BK][BN + 1];
    int tid = threadIdx.x;
    int bm = blockIdx.y * BM, bn = blockIdx.x * BN;
    int lm  = tid >> 2;
    int lk4 = (tid & 3) * 4;
    int tm = (tid >> 4) * 4, tn = (tid & 15) * 4;
    double acc[4][4] = {};
    for (int k0 = 0; k0 < Kd; k0 += BK) {
        {
            const float* p = A + (size_t)(bm + lm) * lda + k0 + lk4;
            #pragma unroll
            for (int i = 0; i < 4; ++i) As[lk4 + i][lm] = p[i];
        }
        {
            const float* p = B + (size_t)(bn + lm) * ldb + k0 + lk4;
            #pragma unroll
            for (int i = 0; i < 4; ++i) Bs[lk4 + i][lm] = p[i];
        }
        __syncthreads();
        #pragma unroll
        for (int k = 0; k < BK; ++k) {
            float av[4], bw[4];
            #pragma unroll
            for (int i = 0; i < 4; ++i) av[i] = As[k][tm + i];
            #pragma unroll
            for (int j = 0; j < 4; ++j) bw[j] = Bs[k][tn + j];
            #pragma unroll
            for (int i = 0; i < 4; ++i)
                #pragma unroll
                for (int j = 0; j < 4; ++j)
                    acc[i][j] += (double)av[i] * (double)bw[j];
        }
        __syncthreads();
    }
    #pragma unroll
    for (int i = 0; i < 4; ++i) {
        int m = bm + tm + i;
        #pragma unroll
        for (int j = 0; j < 4; ++j) {
            int n = bn + tn + j;
            double v = acc[i][j] + (double)bias[n];
            size_t idx = (size_t)(n >> 6) * ((size_t)M * 64) + (size_t)m * 64 + (n & 63);
            out[idx] = (float)v;
        }
    }
}

// ============================ logits GEMM (z = chunk), f32 acc, bf16 out ===================
__global__ __launch_bounds__(256)
void logits_kernel(const float* __restrict__ normed, const float* __restrict__ W1,
                   const int* __restrict__ sids, const float* __restrict__ b1,
                   bf16* __restrict__ logits)
{
    const int lda = 1024, ldb = 1024, ldc = 1024, Kd = 1024;
    size_t chOff = (size_t)blockIdx.z * 1048576;
    const float* A = normed + chOff;
    const int* gk = sids + blockIdx.z * 1024;
    bf16* out = logits + chOff;
    __shared__ float As[BK][BM + 1];
    __shared__ float Bs[BK][BN + 1];
    int tid = threadIdx.x;
    int bm = blockIdx.y * BM, bn = blockIdx.x * BN;
    int lm  = tid >> 2;
    int lk4 = (tid & 3) * 4;
    int tm = (tid >> 4) * 4, tn = (tid & 15) * 4;
    float acc[4][4] = {};
    for (int k0 = 0; k0 < Kd; k0 += BK) {
        {
            const float* p = A + (size_t)(bm + lm) * lda + k0 + lk4;
            #pragma unroll
            for (int i = 0; i < 4; ++i) As[lk4 + i][lm] = p[i];
        }
        {
            int r = gk[bn + lm] & 4095;
            const float* p = W1 + (size_t)r * ldb + k0 + lk4;
            #pragma unroll
            for (int i = 0; i < 4; ++i) Bs[lk4 + i][lm] = p[i];
        }
        __syncthreads();
        #pragma unroll
        for (int k = 0; k < BK; ++k) {
            float av[4], bw[4];
            #pragma unroll
            for (int i = 0; i < 4; ++i) av[i] = As[k][tm + i];
            #pragma unroll
            for (int j = 0; j < 4; ++j) bw[j] = Bs[k][tn + j];
            #pragma unroll
            for (int i = 0; i < 4; ++i)
                #pragma unroll
                for (int j = 0; j < 4; ++j)
                    acc[i][j] += av[i] * bw[j];
        }
        __syncthreads();
    }
    #pragma unroll
    for (int i = 0; i < 4; ++i) {
        int m = bm + tm + i;
        #pragma unroll
        for (int j = 0; j < 4; ++j) {
            int n = bn + tn + j;
            float v = acc[i][j] + b1[gk[n] & 4095];
            out[(size_t)m * ldc + n] = __float2bfloat16(v);
        }
    }
}

// ==== output GEMM (z = chunk): gelu(logits) @ W2[sids] + b2 + attnO -> d_out ====
__global__ __launch_bounds__(256)
void out_kernel(const bf16* __restrict__ logits, const float* __restrict__ W2,
                const int* __restrict__ sids, const float* __restrict__ b2w,
                const float* __restrict__ attnO, float* __restrict__ out)
{
    const int lda = 1024, ldb = 1024, ldc = 1024, Kd = 1024;
    size_t chOff = (size_t)blockIdx.z * 1048576;
    const bf16* A = logits + chOff;
    const int* gk = sids + blockIdx.z * 1024;
    const float* residual = attnO + chOff;
    __shared__ float As[BK][BM + 1];
    __shared__ float Bs[BK][BN + 1];
    int tid = threadIdx.x;
    int bm = blockIdx.y * BM, bn = blockIdx.x * BN;
    int lm  = tid >> 2;
    int lk4 = (tid & 3) * 4;
    int bkr = tid >> 4;
    int bn4 = (tid & 15) * 4;
    int tm = (tid >> 4) * 4, tn = (tid & 15) * 4;
    float acc[4][4] = {};
    for (int k0 = 0; k0 < Kd; k0 += BK) {
        {
            const bf16* p = A + (size_t)(bm + lm) * lda + k0 + lk4;
            #pragma unroll
            for (int i = 0; i < 4; ++i) {
                float x = b2f(p[i]);
                As[lk4 + i][lm] = 0.5f * x * (1.0f + erff(x * 0.70710678118654752f));
            }
        }
        {
            int r = gk[k0 + bkr] & 4095;
            const float* q = W2 + (size_t)r * ldb + bn + bn4;
            #pragma unroll
            for (int i = 0; i < 4; ++i) Bs[bkr][bn4 + i] = q[i];
        }
        __syncthreads();
        #pragma unroll
        for (int k = 0; k < BK; ++k) {
            float av[4], bw[4];
            #pragma unroll
            for (int i = 0; i < 4; ++i) av[i] = As[k][tm + i];
            #pragma unroll
            for (int j = 0; j < 4; ++j) bw[j] = Bs[k][tn + j];
            #pragma unroll
            for (int i = 0; i < 4; ++i)
                #pragma unroll
                for (int j = 0; j < 4; ++j)
                    acc[i][j] += av[i] * bw[j];
        }
        __syncthreads();
    }
    #pragma unroll
    for (int i = 0; i < 4; ++i) {
        int m = bm + tm + i;
        #pragma unroll
        for (int j = 0; j < 4; ++j) {
            int n = bn + tn + j;
            float v = acc[i][j] + b2w[n] + residual[(size_t)m * ldc + n];
            out[chOff + (size_t)m * ldc + n] = v;
        }
    }
}

// ============================ flash attention v2 ============================
// Q-tile 32 (grid 64 x 8 per group), f64 accumulation, shfl-parallel softmax.
// LDS ~36KB -> better occupancy. Per-row FP order identical to v1.
__global__ __launch_bounds__(256)
void flash_kernel(const float* __restrict__ q, const float* __restrict__ k,
                  const float* __restrict__ v, const float* __restrict__ amask,
                  float* __restrict__ ctx, int hbase)
{
    int qt = blockIdx.x, hl = blockIdx.y, tid = threadIdx.x;
    int ty = tid >> 4, tx = tid & 15;
    int r0 = ty * 2;                       // rows r0, r0+1 of 32
    __shared__ __align__(16) float Qs[32][68];
    __shared__ __align__(16) float KVs[64][68];   // K in score phase, V in PV phase
    __shared__ float St[32][68];
    __shared__ float mrow[32], msk[64];
    __shared__ double lrow[32];
    const float* qh = q + (size_t)hl * 131072 + (size_t)qt * 2048;
    #pragma unroll
    for (int rep = 0; rep < 2; ++rep) {
        int lin = rep * 1024 + tid * 4;
        int r = lin >> 6, c = lin & 63;
        float4 u = *(const float4*)(qh + r * 64 + c);
        Qs[r][c] = u.x; Qs[r][c+1] = u.y; Qs[r][c+2] = u.z; Qs[r][c+3] = u.w;
    }
    if (tid < 32) { mrow[tid] = NEG_INF; lrow[tid] = 0.0; }
    double o0[4] = {}, o1[4] = {};
    for (int kt = 0; kt < 32; ++kt) {
        const float* kh = k + (size_t)hl * 131072 + (size_t)kt * 4096;
        const float* vh = v + (size_t)hl * 131072 + (size_t)kt * 4096;
        #pragma unroll
        for (int rep = 0; rep < 4; ++rep) {
            int lin = rep * 1024 + tid * 4;
            int r = lin >> 6, c = lin & 63;
            float4 u = *(const float4*)(kh + r * 64 + c);
            KVs[r][c] = u.x; KVs[r][c+1] = u.y; KVs[r][c+2] = u.z; KVs[r][c+3] = u.w;
        }
        if (tid < 64) msk[tid] = 1000.0f * (1.0f - amask[kt * 64 + tid]);
        __syncthreads();
        // scores, f64 acc (same per-(r,c) add order as v1)
        double sc0[4] = {}, sc1[4] = {};
        #pragma unroll 4
        for (int d = 0; d < 64; d += 4) {
            float4 q0 = *(const float4*)&Qs[r0][d];
            float4 q1 = *(const float4*)&Qs[r0 + 1][d];
            #pragma unroll
            for (int j = 0; j < 4; ++j) {
                float4 kv = *(const float4*)&KVs[tx * 4 + j][d];
                sc0[j] += (double)q0.x * kv.x + (double)q0.y * kv.y + (double)q0.z * kv.z + (double)q0.w * kv.w;
                sc1[j] += (double)q1.x * kv.x + (double)q1.y * kv.y + (double)q1.z * kv.z + (double)q1.w * kv.w;
            }
        }
        __syncthreads();   // K reads done -> KVs free for V
        float s0[4], s1[4];
        #pragma unroll
        for (int j = 0; j < 4; ++j) {
            s0[j] = (float)(sc0[j] * 0.125) - msk[tx * 4 + j];
            s1[j] = (float)(sc1[j] * 0.125) - msk[tx * 4 + j];
        }
        // row max via width-16 shfl (16 owner lanes of a row are contiguous in one wave)
        float mx0 = fmaxf(fmaxf(s0[0], s0[1]), fmaxf(s0[2], s0[3]));
        float mx1 = fmaxf(fmaxf(s1[0], s1[1]), fmaxf(s1[2], s1[3]));
        #pragma unroll
        for (int off = 1; off < 16; off <<= 1) {
            mx0 = fmaxf(mx0, __shfl_xor(mx0, off, 16));
            mx1 = fmaxf(mx1, __shfl_xor(mx1, off, 16));
        }
        float mo0 = mrow[r0], mo1 = mrow[r0 + 1];
        float m0 = fmaxf(mo0, mx0), m1 = fmaxf(mo1, mx1);
        float al0 = expf(mo0 - m0), al1 = expf(mo1 - m1);
        float sum0 = 0.0f, sum1 = 0.0f;
        #pragma unroll
        for (int j = 0; j < 4; ++j) {
            float p0 = expf(s0[j] - m0), p1 = expf(s1[j] - m1);
            St[r0][tx * 4 + j] = p0; St[r0 + 1][tx * 4 + j] = p1;
            sum0 += p0; sum1 += p1;
        }
        #pragma unroll
        for (int off = 1; off < 16; off <<= 1) {
            sum0 += __shfl_xor(sum0, off, 16);
            sum1 += __shfl_xor(sum1, off, 16);
        }
        if (tx == 0) {
            lrow[r0]     = lrow[r0]     * al0 + sum0;
            lrow[r0 + 1] = lrow[r0 + 1] * al1 + sum1;
            mrow[r0] = m0; mrow[r0 + 1] = m1;
        }
        #pragma unroll
        for (int j = 0; j < 4; ++j) { o0[j] *= al0; o1[j] *= al1; }
        // load V into KVs
        #pragma unroll
        for (int rep = 0; rep < 4; ++rep) {
            int lin = rep * 1024 + tid * 4;
            int r = lin >> 6, c = lin & 63;
            float4 w = *(const float4*)(vh + r * 64 + c);
            KVs[r][c] = w.x; KVs[r][c+1] = w.y; KVs[r][c+2] = w.z; KVs[r][c+3] = w.w;
        }
        __syncthreads();   // V + St ready
        for (int j2 = 0; j2 < 64; ++j2) {
            float4 vv = *(const float4*)&KVs[j2][tx * 4];
            double p0 = St[r0][j2], p1 = St[r0 + 1][j2];
            o0[0] += p0 * vv.x; o0[1] += p0 * vv.y; o0[2] += p0 * vv.z; o0[3] += p0 * vv.w;
            o1[0] += p1 * vv.x; o1[1] += p1 * vv.y; o1[2] += p1 * vv.z; o1[3] += p1 * vv.w;
        }
        __syncthreads();   // protect KVs/St for next kt
    }
    double inv0 = 1.0 / lrow[r0], inv1 = 1.0 / lrow[r0 + 1];
    size_t base0 = (size_t)(qt * 32 + r0) * 1024 + (hbase + hl) * 64 + tx * 4;
    size_t base1 = base0 + 1024;
    #pragma unroll
    for (int j = 0; j < 4; ++j) {
        ctx[base0 + j] = (float)(o0[j] * inv0);
        ctx[base1 + j] = (float)(o1[j] * inv1);
    }
}

// ============================ hashing / routing ============================
__global__ __launch_bounds__(256)
void code_n_kernel(const float* __restrict__ projn, int* __restrict__ code_n)
{
    int i = blockIdx.x * 256 + threadIdx.x;
    const float* p = projn + (size_t)i * 8;
    int code = 0;
    #pragma unroll
    for (int k = 0; k < 8; ++k) code |= ((int)(p[k] > 0.0f)) << k;
    code_n[i] = code;
}

__global__ __launch_bounds__(256)
void code_t_kernel(float* __restrict__ pt, int* __restrict__ code_t)
{
    int i = blockIdx.x * 256 + threadIdx.x;
    int t = i >> 4, l = i & 15;
    float* p = pt + (size_t)t * 128 + l * 8;
    int code = 0;
    #pragma unroll
    for (int k = 0; k < 8; ++k) {
        float v = p[k];
        code |= ((int)(v > 0.0f)) << k;
        p[k] = tanhf(v);
    }
    code_t[l * 2048 + t] = code;
}

__global__ __launch_bounds__(256)
void hist_kernel(const int* __restrict__ code_t, int* __restrict__ hist)
{
    int i = blockIdx.x * 256 + threadIdx.x;
    int c = i >> 14, l = (i >> 10) & 15, t = i & 1023;
    int code = code_t[l * 2048 + c * 1024 + t] & 255;
    atomicAdd(&hist[(c * 16 + l) * 256 + code], 1);
}

__global__ __launch_bounds__(256)
void score_kernel(const int* __restrict__ hist, const int* __restrict__ code_n,
                  int* __restrict__ score, int* __restrict__ shist)
{
    int i = blockIdx.x * 256 + threadIdx.x;
    int c = i >> 12, n = i & 4095;
    int s = 0;
    #pragma unroll
    for (int l = 0; l < 16; ++l) s += hist[(c * 16 + l) * 256 + (code_n[l * 4096 + n] & 255)];
    if (s < 0) s = 0; if (s > 16384) s = 16384;
    score[c * 4096 + n] = s;
    atomicAdd(&shist[c * 16385 + s], 1);
}

__global__ __launch_bounds__(256)
void select_kernel(const int* __restrict__ shist, int* __restrict__ selmeta)
{
    int c = blockIdx.x, tid = threadIdx.x;
    const int* bins = shist + c * 16385;
    __shared__ int psum[256];
    int s = 0;
    for (int i = 0; i < 64; ++i) s += bins[tid * 64 + i];
    if (tid == 255) s += bins[16384];
    psum[tid] = s;
    __syncthreads();
    if (tid == 0) {
        int cum = 0, sstar = 0, cntge = 0;
        for (int t = 255; t >= 0; --t) {
            if (cum + psum[t] >= 1024) {
                int hi = (t == 255) ? 16384 : t * 64 + 63;
                for (int b = hi; b >= t * 64; --b) {
                    cum += bins[b];
                    if (cum >= 1024) { sstar = b; cntge = cum; break; }
                }
                break;
            }
            cum += psum[t];
        }
        selmeta[c * 2]     = sstar;
        selmeta[c * 2 + 1] = 1024 - (cntge - bins[sstar]);
    }
}

__global__ __launch_bounds__(256)
void build_sids_kernel(const int* __restrict__ score, const int* __restrict__ selmeta,
                       int* __restrict__ sids)
{
    int c = blockIdx.x, tid = threadIdx.x;
    const int* sc2 = score + c * 4096;
    int sstar = selmeta[c * 2], need_eq = selmeta[c * 2 + 1];
    __shared__ int scan[256];
    int base = tid * 16;
    int mysc[16];
    int eqc = 0;
    #pragma unroll
    for (int i = 0; i < 16; ++i) { mysc[i] = sc2[base + i]; eqc += (mysc[i] == sstar); }
    scan[tid] = eqc; __syncthreads();
    for (int o = 1; o < 256; o <<= 1) {
        int v = (tid >= o) ? scan[tid - o] : 0;
        __syncthreads();
        scan[tid] += v;
        __syncthreads();
    }
    int eqr = scan[tid] - eqc;
    __syncthreads();
    int selc = 0; unsigned flags = 0;
    #pragma unroll
    for (int i = 0; i < 16; ++i) {
        bool sel = false;
        if (mysc[i] > sstar) sel = true;
        else if (mysc[i] == sstar) { sel = (eqr < need_eq); eqr++; }
        if (sel) { flags |= (1u << i); selc++; }
    }
    scan[tid] = selc; __syncthreads();
    for (int o = 1; o < 256; o <<= 1) {
        int v = (tid >= o) ? scan[tid - o] : 0;
        __syncthreads();
        scan[tid] += v;
        __syncthreads();
    }
    int pos = scan[tid] - selc;
    #pragma unroll
    for (int i = 0; i < 16; ++i)
        if (flags & (1u << i)) { if (pos < 1024) sids[c * 1024 + pos] = base + i; pos++; }
}

__global__ __launch_bounds__(256)
void tanhpn_kernel(const float* __restrict__ projn, const int* __restrict__ sids,
                   float* __restrict__ tanhpn)
{
    int i = blockIdx.x * 256 + threadIdx.x;
    int c = i >> 17;
    int r = i & 131071;
    int s = r >> 7, j = r & 127;
    int l = j >> 3, k = j & 7;
    int n = sids[c * 1024 + s] & 4095;
    tanhpn[(size_t)c * 131072 + (size_t)s * 128 + j] = tanhf(projn[(size_t)l * 32768 + (size_t)n * 8 + k]);
}

// ============================ per-row top-64 pos/neg + triplet (shfl argmax) ===============
__global__ __launch_bounds__(256)
void topk_kernel(const bf16* __restrict__ logits, const float* __restrict__ tanhpt,
                 const float* __restrict__ tanhpn, float* __restrict__ trip)
{
    int t = blockIdx.x;
    int c = t >> 10, tid = threadIdx.x;
    __shared__ float agr[1024];
    __shared__ float qrow[128];
    __shared__ float wv_[4];
    __shared__ int   wi_[4];
    __shared__ int   bcast;
    if (tid < 128) qrow[tid] = tanhpt[(size_t)t * 128 + tid];
    __syncthreads();
    for (int s = tid; s < 1024; s += 256) {
        const float* pn = tanhpn + ((size_t)c * 1024 + s) * 128;
        float acc = 0.0f;
        #pragma unroll 8
        for (int d = 0; d < 128; ++d) acc += qrow[d] * pn[d];
        agr[s] = acc * (1.0f / 128.0f);
    }
    const bf16* lrow = logits + (size_t)t * 1024;
    float base[4];
    #pragma unroll
    for (int r = 0; r < 4; ++r) base[r] = b2f(lrow[r * 256 + tid]);   // idx = r*256+tid
    __syncthreads();
    float mres[2];
    for (int p = 0; p < 2; ++p) {
        float mv[4];
        #pragma unroll
        for (int r = 0; r < 4; ++r) mv[r] = p ? -base[r] : base[r];
        float asum = 0.0f;
        for (int it = 0; it < 64; ++it) {
            float bv = mv[0]; int bi = tid;
            #pragma unroll
            for (int r = 1; r < 4; ++r)
                if (mv[r] > bv) { bv = mv[r]; bi = r * 256 + tid; }
            #pragma unroll
            for (int off = 1; off < 64; off <<= 1) {
                float ov = __shfl_xor(bv, off, 64);
                int   oi = __shfl_xor(bi, off, 64);
                if (ov > bv || (ov == bv && oi < bi)) { bv = ov; bi = oi; }
            }
            if ((tid & 63) == 0) { wv_[tid >> 6] = bv; wi_[tid >> 6] = bi; }
            __syncthreads();
            if (tid == 0) {
                float fv = wv_[0]; int fi = wi_[0];
                #pragma unroll
                for (int w = 1; w < 4; ++w) {
                    float ov = wv_[w]; int oi = wi_[w];
                    if (ov > fv || (ov == fv && oi < fi)) { fv = ov; fi = oi; }
                }
                asum += agr[fi];
                bcast = fi;
            }
            __syncthreads();
            int w = bcast;
            if ((w & 255) == tid) mv[w >> 8] = NEG_INF;
        }
        mres[p] = asum * (1.0f / 64.0f);
    }
    if (tid == 0) {
        float v = mres[1] - mres[0] + 0.5f;
        trip[t] = v > 0.0f ? v : 0.0f;
    }
}

__global__ __launch_bounds__(256)
void trip_mean_kernel(const float* __restrict__ trip, float* __restrict__ out)
{
    int tid = threadIdx.x;
    float s = 0.0f;
    for (int i = tid; i < 2048; i += 256) s += trip[i];
    __shared__ float rs[256];
    rs[tid] = s; __syncthreads();
    for (int o = 128; o > 0; o >>= 1) { if (tid < o) rs[tid] += rs[tid + o]; __syncthreads(); }
    if (tid == 0) out[2097152] = rs[0] * (1.0f / 2048.0f);
}

// ============================ launch ============================
extern "C" void kernel_launch(void* const* d_in, const int* in_sizes, int n_in,
                              void* d_out, int out_size, void* d_ws, size_t ws_size,
                              hipStream_t stream)
{
    const float* hidden = (const float*)d_in[0];
    const float* amask  = (const float*)d_in[1];
    const float* ln1g   = (const float*)d_in[2];
    const float* ln1b   = (const float*)d_in[3];
    const float* Wq     = (const float*)d_in[4];
    const float* bq     = (const float*)d_in[5];
    const float* Wk     = (const float*)d_in[6];
    const float* bk     = (const float*)d_in[7];
    const float* Wv     = (const float*)d_in[8];
    const float* bv     = (const float*)d_in[9];
    const float* Wo     = (const float*)d_in[10];
    const float* bo     = (const float*)d_in[11];
    const float* ln2g   = (const float*)d_in[12];
    const float* ln2b   = (const float*)d_in[13];
    const float* W1     = (const float*)d_in[14];
    const float* b1     = (const float*)d_in[15];
    const float* Whash  = (const float*)d_in[16];
    const float* W2     = (const float*)d_in[17];
    const float* b2w    = (const float*)d_in[18];
    float* out = (float*)d_out;
    float* ws  = (float*)d_ws;
    const size_t MB = 1024 * 1024;
    if (ws_size < 20 * MB) return;

    // ---- ws layout (floats), 20 MB ----
    float* xln    = ws;                 // [0,8MB)
    float* qg     = ws + 2097152;       // [8,12MB)
    float* kg     = ws + 3145728;       // [12,16MB)
    float* vg     = ws + 4194304;       // [16,20MB)
    float* attnO  = ws + 2097152;       // [8,16MB) after flash
    float* normed = ws;                 // [0,8MB)
    bf16*  logits = (bf16*)(ws + 4194304); // [16,20MB)
    int*   sids_ws = (int*)ws;          // [0,8KB) after normed dead

    // ---- d_out scratch layout (floats) ----
    float* ctx    = out;
    float* projn  = out;
    float* tanhpt = out + 524288;
    float* tanhpn = out + 786432;
    int*   dints  = (int*)out + 1048576;
    int*   code_n = dints;
    int*   code_t = dints + 65536;
    int*   hist   = dints + 98304;
    int*   score  = dints + 106496;
    int*   shist  = dints + 114688;
    int*   selmeta= dints + 147460;
    int*   sids   = dints + 147464;
    float* trip   = (float*)(dints + 149512);

    // ---- attention (2 head-groups of 8; f64 accumulation throughout) ----
    ln_kernel<<<2048, 256, 0, stream>>>(hidden, ln1g, ln1b, xln);
    for (int g = 0; g < 2; ++g) {
        const size_t wOff = (size_t)g * 512 * 1024;
        qkv_kernel<<<dim3(8, 32, 3), 256, 0, stream>>>(xln, Wq + wOff, Wk + wOff, Wv + wOff,
                                                       bq + g * 512, bk + g * 512, bv + g * 512,
                                                       qg, kg, vg);
        flash_kernel<<<dim3(64, 8), 256, 0, stream>>>(qg, kg, vg, amask, ctx, g * 8);
    }
    gemm_nt_t<double><<<dim3(16, 32), 256, 0, stream>>>(ctx, 1024, Wo, 1024, nullptr, bo, hidden, attnO, 0, 1024, 0, 2048, 1024, 1024);

    // ---- FFN routing ----
    ln_kernel<<<2048, 256, 0, stream>>>(attnO, ln2g, ln2b, normed);
    gemm_nt_t<double><<<dim3(2, 64), 256, 0, stream>>>(W1, 1024, Whash, 1024, nullptr, nullptr, nullptr, projn, 0, 0, 3, 4096, 128, 1024);
    code_n_kernel<<<256, 256, 0, stream>>>(projn, code_n);
    gemm_nt_t<double><<<dim3(2, 32), 256, 0, stream>>>(normed, 1024, Whash, 1024, nullptr, nullptr, nullptr, tanhpt, 0, 128, 0, 2048, 128, 1024);
    zero_kernel<<<193, 256, 0, stream>>>(hist, 49156);
    code_t_kernel<<<128, 256, 0, stream>>>(tanhpt, code_t);
    hist_kernel<<<128, 256, 0, stream>>>(code_t, hist);
    score_kernel<<<32, 256, 0, stream>>>(hist, code_n, score, shist);
    select_kernel<<<2, 256, 0, stream>>>(shist, selmeta);
    build_sids_kernel<<<2, 256, 0, stream>>>(score, selmeta, sids);
    tanhpn_kernel<<<1024, 256, 0, stream>>>(projn, sids, tanhpn);

    // ---- logits (bf16, ws; f32 acc), both chunks in one launch ----
    logits_kernel<<<dim3(16, 16, 2), 256, 0, stream>>>(normed, W1, sids, b1, logits);

    // ---- triplet (reads d_out scratch; must precede final writes) ----
    topk_kernel<<<2048, 256, 0, stream>>>(logits, tanhpt, tanhpn, trip);
    trip_mean_kernel<<<1, 256, 0, stream>>>(trip, out);

    // ---- final FFN output (overwrites d_out matrix) ----
    copy_int_kernel<<<8, 256, 0, stream>>>(sids, sids_ws, 2048);
    out_kernel<<<dim3(16, 16, 2), 256, 0, stream>>>(logits, W2, sids_ws, b2w, attnO, out);
}

// Round 10
// 2009.570 us; speedup vs baseline: 1.5492x; 1.1115x over previous
//
#include <hip/hip_runtime.h>
#include <hip/hip_bf16.h>
#include <math.h>

typedef __hip_bfloat16 bf16;
__device__ __forceinline__ float b2f(bf16 x) { return __bfloat162float(x); }

#define LN_EPS 1e-12f
#define NEG_INF (-3.0e38f)

__global__ __launch_bounds__(256)
void zero_kernel(int* __restrict__ p, int n)
{
    int i = blockIdx.x * 256 + threadIdx.x;
    if (i < n) p[i] = 0;
}

__global__ __launch_bounds__(256)
void copy_int_kernel(const int* __restrict__ src, int* __restrict__ dst, int n)
{
    int i = blockIdx.x * 256 + threadIdx.x;
    if (i < n) dst[i] = src[i];
}

// ============================ LayerNorm (f32 -> f32, f64 stats) ============================
__global__ __launch_bounds__(256)
void ln_kernel(const float* __restrict__ in, const float* __restrict__ g,
               const float* __restrict__ b, float* __restrict__ out)
{
    const int D = 1024;
    int row = blockIdx.x, tid = threadIdx.x;
    size_t base = (size_t)row * D + tid * 4;
    float x[4];
    #pragma unroll
    for (int i = 0; i < 4; ++i) x[i] = in[base + i];
    double s  = (double)x[0] + x[1] + x[2] + x[3];
    double sq = (double)x[0]*x[0] + (double)x[1]*x[1] + (double)x[2]*x[2] + (double)x[3]*x[3];
    __shared__ double rs[256], rq[256];
    rs[tid] = s; rq[tid] = sq;
    __syncthreads();
    for (int o = 128; o > 0; o >>= 1) {
        if (tid < o) { rs[tid] += rs[tid + o]; rq[tid] += rq[tid + o]; }
        __syncthreads();
    }
    double mean = rs[0] * (1.0 / D);
    double var  = rq[0] * (1.0 / D) - mean * mean;
    double inv  = rsqrt(var + (double)LN_EPS);
    #pragma unroll
    for (int i = 0; i < 4; ++i) {
        int col = tid * 4 + i;
        out[base + i] = (float)(((double)x[i] - mean) * inv * (double)g[col] + (double)b[col]);
    }
}

// ============================ generic NT GEMM (f32 storage, templated accumulator) =========
// LDS pad +4 keeps 16B alignment -> ds_read_b128 operand fetch.
#define BM 64
#define BN 64
#define BK 16
template<typename ACC>
__global__ __launch_bounds__(256)
void gemm_nt_t(const float* __restrict__ A, int lda,
               const float* __restrict__ B, int ldb,
               const int* __restrict__ gatherB,
               const float* __restrict__ bias,
               const float* __restrict__ residual,
               void* __restrict__ out_, int oBf, int ldc, int mode,
               int M, int N, int Kd)
{
    __shared__ __align__(16) float As[BK][BM + 4];
    __shared__ __align__(16) float Bs[BK][BN + 4];
    int tid = threadIdx.x;
    int bm = blockIdx.y * BM, bn = blockIdx.x * BN;
    int lm  = tid >> 2;
    int lk4 = (tid & 3) * 4;
    int tm = (tid >> 4) * 4, tn = (tid & 15) * 4;
    ACC acc[4][4] = {};
    for (int k0 = 0; k0 < Kd; k0 += BK) {
        {
            const float* p = A + (size_t)(bm + lm) * lda + k0 + lk4;
            #pragma unroll
            for (int i = 0; i < 4; ++i) As[lk4 + i][lm] = p[i];
        }
        {
            int r = bn + lm;
            if (gatherB) r = gatherB[r] & 4095;
            const float* p = B + (size_t)r * ldb + k0 + lk4;
            #pragma unroll
            for (int i = 0; i < 4; ++i) Bs[lk4 + i][lm] = p[i];
        }
        __syncthreads();
        #pragma unroll
        for (int k = 0; k < BK; ++k) {
            float4 av = *(const float4*)&As[k][tm];
            float4 bw = *(const float4*)&Bs[k][tn];
            float avx[4] = {av.x, av.y, av.z, av.w};
            float bwx[4] = {bw.x, bw.y, bw.z, bw.w};
            #pragma unroll
            for (int i = 0; i < 4; ++i)
                #pragma unroll
                for (int j = 0; j < 4; ++j)
                    acc[i][j] += (ACC)avx[i] * (ACC)bwx[j];
        }
        __syncthreads();
    }
    #pragma unroll
    for (int i = 0; i < 4; ++i) {
        int m = bm + tm + i;
        #pragma unroll
        for (int j = 0; j < 4; ++j) {
            int n = bn + tn + j;
            ACC v = acc[i][j];
            if (bias) { int bi2 = gatherB ? (gatherB[n] & 4095) : n; v += (ACC)bias[bi2]; }
            if (residual) v += (ACC)residual[(size_t)m * ldc + n];
            size_t idx;
            if (mode == 0)      idx = (size_t)m * ldc + n;
            else if (mode == 1) idx = (size_t)(n >> 6) * ((size_t)M * 64) + (size_t)m * 64 + (n & 63);
            else                idx = (size_t)(n >> 3) * ((size_t)M * 8) + (size_t)m * 8 + (n & 7);
            if (oBf) ((bf16*)out_)[idx] = __float2bfloat16((float)v);
            else     ((float*)out_)[idx] = (float)v;
        }
    }
}

// ============================ QKV fused (z selects Q/K/V), f64 acc, mode1 out ==============
__global__ __launch_bounds__(256)
void qkv_kernel(const float* __restrict__ A,
                const float* __restrict__ Wq, const float* __restrict__ Wk, const float* __restrict__ Wv,
                const float* __restrict__ bq, const float* __restrict__ bk, const float* __restrict__ bv,
                float* __restrict__ qo, float* __restrict__ ko, float* __restrict__ vo)
{
    const int lda = 1024, ldb = 1024, Kd = 1024, M = 2048;
    const float* B    = (blockIdx.z == 0) ? Wq : (blockIdx.z == 1) ? Wk : Wv;
    const float* bias = (blockIdx.z == 0) ? bq : (blockIdx.z == 1) ? bk : bv;
    float* out        = (blockIdx.z == 0) ? qo : (blockIdx.z == 1) ? ko : vo;
    __shared__ __align__(16) float As[BK][BM + 4];
    __shared__ __align__(16) float Bs[BK][BN + 4];
    int tid = threadIdx.x;
    int bm = blockIdx.y * BM, bn = blockIdx.x * BN;
    int lm  = tid >> 2;
    int lk4 = (tid & 3) * 4;
    int tm = (tid >> 4) * 4, tn = (tid & 15) * 4;
    double acc[4][4] = {};
    for (int k0 = 0; k0 < Kd; k0 += BK) {
        {
            const float* p = A + (size_t)(bm + lm) * lda + k0 + lk4;
            #pragma unroll
            for (int i = 0; i < 4; ++i) As[lk4 + i][lm] = p[i];
        }
        {
            const float* p = B + (size_t)(bn + lm) * ldb + k0 + lk4;
            #pragma unroll
            for (int i = 0; i < 4; ++i) Bs[lk4 + i][lm] = p[i];
        }
        __syncthreads();
        #pragma unroll
        for (int k = 0; k < BK; ++k) {
            float4 av = *(const float4*)&As[k][tm];
            float4 bw = *(const float4*)&Bs[k][tn];
            float avx[4] = {av.x, av.y, av.z, av.w};
            float bwx[4] = {bw.x, bw.y, bw.z, bw.w};
            #pragma unroll
            for (int i = 0; i < 4; ++i)
                #pragma unroll
                for (int j = 0; j < 4; ++j)
                    acc[i][j] += (double)avx[i] * (double)bwx[j];
        }
        __syncthreads();
    }
    #pragma unroll
    for (int i = 0; i < 4; ++i) {
        int m = bm + tm + i;
        #pragma unroll
        for (int j = 0; j < 4; ++j) {
            int n = bn + tn + j;
            double v = acc[i][j] + (double)bias[n];
            size_t idx = (size_t)(n >> 6) * ((size_t)M * 64) + (size_t)m * 64 + (n & 63);
            out[idx] = (float)v;
        }
    }
}

// ============================ logits GEMM (z = chunk), f32 acc, bf16 out ===================
__global__ __launch_bounds__(256)
void logits_kernel(const float* __restrict__ normed, const float* __restrict__ W1,
                   const int* __restrict__ sids, const float* __restrict__ b1,
                   bf16* __restrict__ logits)
{
    const int lda = 1024, ldb = 1024, ldc = 1024, Kd = 1024;
    size_t chOff = (size_t)blockIdx.z * 1048576;
    const float* A = normed + chOff;
    const int* gk = sids + blockIdx.z * 1024;
    bf16* out = logits + chOff;
    __shared__ __align__(16) float As[BK][BM + 4];
    __shared__ __align__(16) float Bs[BK][BN + 4];
    int tid = threadIdx.x;
    int bm = blockIdx.y * BM, bn = blockIdx.x * BN;
    int lm  = tid >> 2;
    int lk4 = (tid & 3) * 4;
    int tm = (tid >> 4) * 4, tn = (tid & 15) * 4;
    float acc[4][4] = {};
    for (int k0 = 0; k0 < Kd; k0 += BK) {
        {
            const float* p = A + (size_t)(bm + lm) * lda + k0 + lk4;
            #pragma unroll
            for (int i = 0; i < 4; ++i) As[lk4 + i][lm] = p[i];
        }
        {
            int r = gk[bn + lm] & 4095;
            const float* p = W1 + (size_t)r * ldb + k0 + lk4;
            #pragma unroll
            for (int i = 0; i < 4; ++i) Bs[lk4 + i][lm] = p[i];
        }
        __syncthreads();
        #pragma unroll
        for (int k = 0; k < BK; ++k) {
            float4 av = *(const float4*)&As[k][tm];
            float4 bw = *(const float4*)&Bs[k][tn];
            float avx[4] = {av.x, av.y, av.z, av.w};
            float bwx[4] = {bw.x, bw.y, bw.z, bw.w};
            #pragma unroll
            for (int i = 0; i < 4; ++i)
                #pragma unroll
                for (int j = 0; j < 4; ++j)
                    acc[i][j] += avx[i] * bwx[j];
        }
        __syncthreads();
    }
    #pragma unroll
    for (int i = 0; i < 4; ++i) {
        int m = bm + tm + i;
        #pragma unroll
        for (int j = 0; j < 4; ++j) {
            int n = bn + tn + j;
            float v = acc[i][j] + b1[gk[n] & 4095];
            out[(size_t)m * ldc + n] = __float2bfloat16(v);
        }
    }
}

// ==== output GEMM (z = chunk): gelu(logits) @ W2[sids] + b2 + attnO -> d_out ====
__global__ __launch_bounds__(256)
void out_kernel(const bf16* __restrict__ logits, const float* __restrict__ W2,
                const int* __restrict__ sids, const float* __restrict__ b2w,
                const float* __restrict__ attnO, float* __restrict__ out)
{
    const int lda = 1024, ldb = 1024, ldc = 1024, Kd = 1024;
    size_t chOff = (size_t)blockIdx.z * 1048576;
    const bf16* A = logits + chOff;
    const int* gk = sids + blockIdx.z * 1024;
    const float* residual = attnO + chOff;
    __shared__ __align__(16) float As[BK][BM + 4];
    __shared__ __align__(16) float Bs[BK][BN + 4];
    int tid = threadIdx.x;
    int bm = blockIdx.y * BM, bn = blockIdx.x * BN;
    int lm  = tid >> 2;
    int lk4 = (tid & 3) * 4;
    int bkr = tid >> 4;
    int bn4 = (tid & 15) * 4;
    int tm = (tid >> 4) * 4, tn = (tid & 15) * 4;
    float acc[4][4] = {};
    for (int k0 = 0; k0 < Kd; k0 += BK) {
        {
            const bf16* p = A + (size_t)(bm + lm) * lda + k0 + lk4;
            #pragma unroll
            for (int i = 0; i < 4; ++i) {
                float x = b2f(p[i]);
                As[lk4 + i][lm] = 0.5f * x * (1.0f + erff(x * 0.70710678118654752f));
            }
        }
        {
            int r = gk[k0 + bkr] & 4095;
            const float* q = W2 + (size_t)r * ldb + bn + bn4;
            #pragma unroll
            for (int i = 0; i < 4; ++i) Bs[bkr][bn4 + i] = q[i];
        }
        __syncthreads();
        #pragma unroll
        for (int k = 0; k < BK; ++k) {
            float4 av = *(const float4*)&As[k][tm];
            float4 bw = *(const float4*)&Bs[k][tn];
            float avx[4] = {av.x, av.y, av.z, av.w};
            float bwx[4] = {bw.x, bw.y, bw.z, bw.w};
            #pragma unroll
            for (int i = 0; i < 4; ++i)
                #pragma unroll
                for (int j = 0; j < 4; ++j)
                    acc[i][j] += avx[i] * bwx[j];
        }
        __syncthreads();
    }
    #pragma unroll
    for (int i = 0; i < 4; ++i) {
        int m = bm + tm + i;
        #pragma unroll
        for (int j = 0; j < 4; ++j) {
            int n = bn + tn + j;
            float v = acc[i][j] + b2w[n] + residual[(size_t)m * ldc + n];
            out[chOff + (size_t)m * ldc + n] = v;
        }
    }
}

// ============================ flash attention v3 ============================
// Q-tile 32, f64 accumulation. Score-phase col ownership tx+16j -> 2-way banks (free).
// Softmax partial sums in f64 (order-robust). Per-score FMA order identical to v2.
__global__ __launch_bounds__(256)
void flash_kernel(const float* __restrict__ q, const float* __restrict__ k,
                  const float* __restrict__ v, const float* __restrict__ amask,
                  float* __restrict__ ctx, int hbase)
{
    int qt = blockIdx.x, hl = blockIdx.y, tid = threadIdx.x;
    int ty = tid >> 4, tx = tid & 15;
    int r0 = ty * 2;
    __shared__ __align__(16) float Qs[32][68];
    __shared__ __align__(16) float KVs[64][68];
    __shared__ float St[32][68];
    __shared__ float mrow[32], msk[64];
    __shared__ double lrow[32];
    const float* qh = q + (size_t)hl * 131072 + (size_t)qt * 2048;
    #pragma unroll
    for (int rep = 0; rep < 2; ++rep) {
        int lin = rep * 1024 + tid * 4;
        int r = lin >> 6, c = lin & 63;
        float4 u = *(const float4*)(qh + r * 64 + c);
        Qs[r][c] = u.x; Qs[r][c+1] = u.y; Qs[r][c+2] = u.z; Qs[r][c+3] = u.w;
    }
    if (tid < 32) { mrow[tid] = NEG_INF; lrow[tid] = 0.0; }
    double o0[4] = {}, o1[4] = {};
    for (int kt = 0; kt < 32; ++kt) {
        const float* kh = k + (size_t)hl * 131072 + (size_t)kt * 4096;
        const float* vh = v + (size_t)hl * 131072 + (size_t)kt * 4096;
        #pragma unroll
        for (int rep = 0; rep < 4; ++rep) {
            int lin = rep * 1024 + tid * 4;
            int r = lin >> 6, c = lin & 63;
            float4 u = *(const float4*)(kh + r * 64 + c);
            KVs[r][c] = u.x; KVs[r][c+1] = u.y; KVs[r][c+2] = u.z; KVs[r][c+3] = u.w;
        }
        if (tid < 64) msk[tid] = 1000.0f * (1.0f - amask[kt * 64 + tid]);
        __syncthreads();
        // scores, f64 acc; lane owns cols tx+16j (2-way bank aliasing = free)
        double sc0[4] = {}, sc1[4] = {};
        #pragma unroll 4
        for (int d = 0; d < 64; d += 4) {
            float4 q0 = *(const float4*)&Qs[r0][d];
            float4 q1 = *(const float4*)&Qs[r0 + 1][d];
            #pragma unroll
            for (int j = 0; j < 4; ++j) {
                float4 kv = *(const float4*)&KVs[tx + 16 * j][d];
                sc0[j] += (double)q0.x * kv.x + (double)q0.y * kv.y + (double)q0.z * kv.z + (double)q0.w * kv.w;
                sc1[j] += (double)q1.x * kv.x + (double)q1.y * kv.y + (double)q1.z * kv.z + (double)q1.w * kv.w;
            }
        }
        __syncthreads();   // K reads done -> KVs free for V
        float s0[4], s1[4];
        #pragma unroll
        for (int j = 0; j < 4; ++j) {
            s0[j] = (float)(sc0[j] * 0.125) - msk[tx + 16 * j];
            s1[j] = (float)(sc1[j] * 0.125) - msk[tx + 16 * j];
        }
        float mx0 = fmaxf(fmaxf(s0[0], s0[1]), fmaxf(s0[2], s0[3]));
        float mx1 = fmaxf(fmaxf(s1[0], s1[1]), fmaxf(s1[2], s1[3]));
        #pragma unroll
        for (int off = 1; off < 16; off <<= 1) {
            mx0 = fmaxf(mx0, __shfl_xor(mx0, off, 16));
            mx1 = fmaxf(mx1, __shfl_xor(mx1, off, 16));
        }
        float mo0 = mrow[r0], mo1 = mrow[r0 + 1];
        float m0 = fmaxf(mo0, mx0), m1 = fmaxf(mo1, mx1);
        float al0 = expf(mo0 - m0), al1 = expf(mo1 - m1);
        double sum0 = 0.0, sum1 = 0.0;
        #pragma unroll
        for (int j = 0; j < 4; ++j) {
            float p0 = expf(s0[j] - m0), p1 = expf(s1[j] - m1);
            St[r0][tx + 16 * j] = p0; St[r0 + 1][tx + 16 * j] = p1;
            sum0 += (double)p0; sum1 += (double)p1;
        }
        #pragma unroll
        for (int off = 1; off < 16; off <<= 1) {
            sum0 += __shfl_xor(sum0, off, 16);
            sum1 += __shfl_xor(sum1, off, 16);
        }
        if (tx == 0) {
            lrow[r0]     = lrow[r0]     * al0 + sum0;
            lrow[r0 + 1] = lrow[r0 + 1] * al1 + sum1;
            mrow[r0] = m0; mrow[r0 + 1] = m1;
        }
        #pragma unroll
        for (int j = 0; j < 4; ++j) { o0[j] *= al0; o1[j] *= al1; }
        // load V into KVs
        #pragma unroll
        for (int rep = 0; rep < 4; ++rep) {
            int lin = rep * 1024 + tid * 4;
            int r = lin >> 6, c = lin & 63;
            float4 w = *(const float4*)(vh + r * 64 + c);
            KVs[r][c] = w.x; KVs[r][c+1] = w.y; KVs[r][c+2] = w.z; KVs[r][c+3] = w.w;
        }
        __syncthreads();   // V + St ready
        for (int j2 = 0; j2 < 64; ++j2) {
            float4 vv = *(const float4*)&KVs[j2][tx * 4];
            double p0 = St[r0][j2], p1 = St[r0 + 1][j2];
            o0[0] += p0 * vv.x; o0[1] += p0 * vv.y; o0[2] += p0 * vv.z; o0[3] += p0 * vv.w;
            o1[0] += p1 * vv.x; o1[1] += p1 * vv.y; o1[2] += p1 * vv.z; o1[3] += p1 * vv.w;
        }
        __syncthreads();   // protect KVs/St for next kt
    }
    double inv0 = 1.0 / lrow[r0], inv1 = 1.0 / lrow[r0 + 1];
    size_t base0 = (size_t)(qt * 32 + r0) * 1024 + (hbase + hl) * 64 + tx * 4;
    size_t base1 = base0 + 1024;
    #pragma unroll
    for (int j = 0; j < 4; ++j) {
        ctx[base0 + j] = (float)(o0[j] * inv0);
        ctx[base1 + j] = (float)(o1[j] * inv1);
    }
}

// ============================ hashing / routing ============================
__global__ __launch_bounds__(256)
void code_n_kernel(const float* __restrict__ projn, int* __restrict__ code_n)
{
    int i = blockIdx.x * 256 + threadIdx.x;
    const float* p = projn + (size_t)i * 8;
    int code = 0;
    #pragma unroll
    for (int k = 0; k < 8; ++k) code |= ((int)(p[k] > 0.0f)) << k;
    code_n[i] = code;
}

__global__ __launch_bounds__(256)
void code_t_kernel(float* __restrict__ pt, int* __restrict__ code_t)
{
    int i = blockIdx.x * 256 + threadIdx.x;
    int t = i >> 4, l = i & 15;
    float* p = pt + (size_t)t * 128 + l * 8;
    int code = 0;
    #pragma unroll
    for (int k = 0; k < 8; ++k) {
        float v = p[k];
        code |= ((int)(v > 0.0f)) << k;
        p[k] = tanhf(v);
    }
    code_t[l * 2048 + t] = code;
}

__global__ __launch_bounds__(256)
void hist_kernel(const int* __restrict__ code_t, int* __restrict__ hist)
{
    int i = blockIdx.x * 256 + threadIdx.x;
    int c = i >> 14, l = (i >> 10) & 15, t = i & 1023;
    int code = code_t[l * 2048 + c * 1024 + t] & 255;
    atomicAdd(&hist[(c * 16 + l) * 256 + code], 1);
}

__global__ __launch_bounds__(256)
void score_kernel(const int* __restrict__ hist, const int* __restrict__ code_n,
                  int* __restrict__ score, int* __restrict__ shist)
{
    int i = blockIdx.x * 256 + threadIdx.x;
    int c = i >> 12, n = i & 4095;
    int s = 0;
    #pragma unroll
    for (int l = 0; l < 16; ++l) s += hist[(c * 16 + l) * 256 + (code_n[l * 4096 + n] & 255)];
    if (s < 0) s = 0; if (s > 16384) s = 16384;
    score[c * 4096 + n] = s;
    atomicAdd(&shist[c * 16385 + s], 1);
}

__global__ __launch_bounds__(256)
void select_kernel(const int* __restrict__ shist, int* __restrict__ selmeta)
{
    int c = blockIdx.x, tid = threadIdx.x;
    const int* bins = shist + c * 16385;
    __shared__ int psum[256];
    int s = 0;
    for (int i = 0; i < 64; ++i) s += bins[tid * 64 + i];
    if (tid == 255) s += bins[16384];
    psum[tid] = s;
    __syncthreads();
    if (tid == 0) {
        int cum = 0, sstar = 0, cntge = 0;
        for (int t = 255; t >= 0; --t) {
            if (cum + psum[t] >= 1024) {
                int hi = (t == 255) ? 16384 : t * 64 + 63;
                for (int b = hi; b >= t * 64; --b) {
                    cum += bins[b];
                    if (cum >= 1024) { sstar = b; cntge = cum; break; }
                }
                break;
            }
            cum += psum[t];
        }
        selmeta[c * 2]     = sstar;
        selmeta[c * 2 + 1] = 1024 - (cntge - bins[sstar]);
    }
}

__global__ __launch_bounds__(256)
void build_sids_kernel(const int* __restrict__ score, const int* __restrict__ selmeta,
                       int* __restrict__ sids)
{
    int c = blockIdx.x, tid = threadIdx.x;
    const int* sc2 = score + c * 4096;
    int sstar = selmeta[c * 2], need_eq = selmeta[c * 2 + 1];
    __shared__ int scan[256];
    int base = tid * 16;
    int mysc[16];
    int eqc = 0;
    #pragma unroll
    for (int i = 0; i < 16; ++i) { mysc[i] = sc2[base + i]; eqc += (mysc[i] == sstar); }
    scan[tid] = eqc; __syncthreads();
    for (int o = 1; o < 256; o <<= 1) {
        int v = (tid >= o) ? scan[tid - o] : 0;
        __syncthreads();
        scan[tid] += v;
        __syncthreads();
    }
    int eqr = scan[tid] - eqc;
    __syncthreads();
    int selc = 0; unsigned flags = 0;
    #pragma unroll
    for (int i = 0; i < 16; ++i) {
        bool sel = false;
        if (mysc[i] > sstar) sel = true;
        else if (mysc[i] == sstar) { sel = (eqr < need_eq); eqr++; }
        if (sel) { flags |= (1u << i); selc++; }
    }
    scan[tid] = selc; __syncthreads();
    for (int o = 1; o < 256; o <<= 1) {
        int v = (tid >= o) ? scan[tid - o] : 0;
        __syncthreads();
        scan[tid] += v;
        __syncthreads();
    }
    int pos = scan[tid] - selc;
    #pragma unroll
    for (int i = 0; i < 16; ++i)
        if (flags & (1u << i)) { if (pos < 1024) sids[c * 1024 + pos] = base + i; pos++; }
}

__global__ __launch_bounds__(256)
void tanhpn_kernel(const float* __restrict__ projn, const int* __restrict__ sids,
                   float* __restrict__ tanhpn)
{
    int i = blockIdx.x * 256 + threadIdx.x;
    int c = i >> 17;
    int r = i & 131071;
    int s = r >> 7, j = r & 127;
    int l = j >> 3, k = j & 7;
    int n = sids[c * 1024 + s] & 4095;
    tanhpn[(size_t)c * 131072 + (size_t)s * 128 + j] = tanhf(projn[(size_t)l * 32768 + (size_t)n * 8 + k]);
}

// ============================ per-row top-64 pos/neg + triplet (shfl argmax) ===============
__global__ __launch_bounds__(256)
void topk_kernel(const bf16* __restrict__ logits, const float* __restrict__ tanhpt,
                 const float* __restrict__ tanhpn, float* __restrict__ trip)
{
    int t = blockIdx.x;
    int c = t >> 10, tid = threadIdx.x;
    __shared__ float agr[1024];
    __shared__ float qrow[128];
    __shared__ float wv_[4];
    __shared__ int   wi_[4];
    __shared__ int   bcast;
    if (tid < 128) qrow[tid] = tanhpt[(size_t)t * 128 + tid];
    __syncthreads();
    for (int s = tid; s < 1024; s += 256) {
        const float* pn = tanhpn + ((size_t)c * 1024 + s) * 128;
        float acc = 0.0f;
        #pragma unroll 8
        for (int d = 0; d < 128; ++d) acc += qrow[d] * pn[d];
        agr[s] = acc * (1.0f / 128.0f);
    }
    const bf16* lrow = logits + (size_t)t * 1024;
    float base[4];
    #pragma unroll
    for (int r = 0; r < 4; ++r) base[r] = b2f(lrow[r * 256 + tid]);
    __syncthreads();
    float mres[2];
    for (int p = 0; p < 2; ++p) {
        float mv[4];
        #pragma unroll
        for (int r = 0; r < 4; ++r) mv[r] = p ? -base[r] : base[r];
        float asum = 0.0f;
        for (int it = 0; it < 64; ++it) {
            float bv = mv[0]; int bi = tid;
            #pragma unroll
            for (int r = 1; r < 4; ++r)
                if (mv[r] > bv) { bv = mv[r]; bi = r * 256 + tid; }
            #pragma unroll
            for (int off = 1; off < 64; off <<= 1) {
                float ov = __shfl_xor(bv, off, 64);
                int   oi = __shfl_xor(bi, off, 64);
                if (ov > bv || (ov == bv && oi < bi)) { bv = ov; bi = oi; }
            }
            if ((tid & 63) == 0) { wv_[tid >> 6] = bv; wi_[tid >> 6] = bi; }
            __syncthreads();
            if (tid == 0) {
                float fv = wv_[0]; int fi = wi_[0];
                #pragma unroll
                for (int w = 1; w < 4; ++w) {
                    float ov = wv_[w]; int oi = wi_[w];
                    if (ov > fv || (ov == fv && oi < fi)) { fv = ov; fi = oi; }
                }
                asum += agr[fi];
                bcast = fi;
            }
            __syncthreads();
            int w = bcast;
            if ((w & 255) == tid) mv[w >> 8] = NEG_INF;
        }
        mres[p] = asum * (1.0f / 64.0f);
    }
    if (tid == 0) {
        float v = mres[1] - mres[0] + 0.5f;
        trip[t] = v > 0.0f ? v : 0.0f;
    }
}

__global__ __launch_bounds__(256)
void trip_mean_kernel(const float* __restrict__ trip, float* __restrict__ out)
{
    int tid = threadIdx.x;
    float s = 0.0f;
    for (int i = tid; i < 2048; i += 256) s += trip[i];
    __shared__ float rs[256];
    rs[tid] = s; __syncthreads();
    for (int o = 128; o > 0; o >>= 1) { if (tid < o) rs[tid] += rs[tid + o]; __syncthreads(); }
    if (tid == 0) out[2097152] = rs[0] * (1.0f / 2048.0f);
}

// ============================ launch ============================
extern "C" void kernel_launch(void* const* d_in, const int* in_sizes, int n_in,
                              void* d_out, int out_size, void* d_ws, size_t ws_size,
                              hipStream_t stream)
{
    const float* hidden = (const float*)d_in[0];
    const float* amask  = (const float*)d_in[1];
    const float* ln1g   = (const float*)d_in[2];
    const float* ln1b   = (const float*)d_in[3];
    const float* Wq     = (const float*)d_in[4];
    const float* bq     = (const float*)d_in[5];
    const float* Wk     = (const float*)d_in[6];
    const float* bk     = (const float*)d_in[7];
    const float* Wv     = (const float*)d_in[8];
    const float* bv     = (const float*)d_in[9];
    const float* Wo     = (const float*)d_in[10];
    const float* bo     = (const float*)d_in[11];
    const float* ln2g   = (const float*)d_in[12];
    const float* ln2b   = (const float*)d_in[13];
    const float* W1     = (const float*)d_in[14];
    const float* b1     = (const float*)d_in[15];
    const float* Whash  = (const float*)d_in[16];
    const float* W2     = (const float*)d_in[17];
    const float* b2w    = (const float*)d_in[18];
    float* out = (float*)d_out;
    float* ws  = (float*)d_ws;
    const size_t MB = 1024 * 1024;
    if (ws_size < 20 * MB) return;

    // ---- ws layout (floats), 20 MB ----
    float* xln    = ws;                 // [0,8MB)
    float* qg     = ws + 2097152;       // [8,12MB)
    float* kg     = ws + 3145728;       // [12,16MB)
    float* vg     = ws + 4194304;       // [16,20MB)
    float* attnO  = ws + 2097152;       // [8,16MB) after flash
    float* normed = ws;                 // [0,8MB)
    bf16*  logits = (bf16*)(ws + 4194304); // [16,20MB)
    int*   sids_ws = (int*)ws;          // [0,8KB) after normed dead

    // ---- d_out scratch layout (floats) ----
    float* ctx    = out;
    float* projn  = out;
    float* tanhpt = out + 524288;
    float* tanhpn = out + 786432;
    int*   dints  = (int*)out + 1048576;
    int*   code_n = dints;
    int*   code_t = dints + 65536;
    int*   hist   = dints + 98304;
    int*   score  = dints + 106496;
    int*   shist  = dints + 114688;
    int*   selmeta= dints + 147460;
    int*   sids   = dints + 147464;
    float* trip   = (float*)(dints + 149512);

    // ---- attention (2 head-groups of 8; f64 accumulation throughout) ----
    ln_kernel<<<2048, 256, 0, stream>>>(hidden, ln1g, ln1b, xln);
    for (int g = 0; g < 2; ++g) {
        const size_t wOff = (size_t)g * 512 * 1024;
        qkv_kernel<<<dim3(8, 32, 3), 256, 0, stream>>>(xln, Wq + wOff, Wk + wOff, Wv + wOff,
                                                       bq + g * 512, bk + g * 512, bv + g * 512,
                                                       qg, kg, vg);
        flash_kernel<<<dim3(64, 8), 256, 0, stream>>>(qg, kg, vg, amask, ctx, g * 8);
    }
    gemm_nt_t<double><<<dim3(16, 32), 256, 0, stream>>>(ctx, 1024, Wo, 1024, nullptr, bo, hidden, attnO, 0, 1024, 0, 2048, 1024, 1024);

    // ---- FFN routing ----
    ln_kernel<<<2048, 256, 0, stream>>>(attnO, ln2g, ln2b, normed);
    gemm_nt_t<double><<<dim3(2, 64), 256, 0, stream>>>(W1, 1024, Whash, 1024, nullptr, nullptr, nullptr, projn, 0, 0, 3, 4096, 128, 1024);
    code_n_kernel<<<256, 256, 0, stream>>>(projn, code_n);
    gemm_nt_t<double><<<dim3(2, 32), 256, 0, stream>>>(normed, 1024, Whash, 1024, nullptr, nullptr, nullptr, tanhpt, 0, 128, 0, 2048, 128, 1024);
    zero_kernel<<<193, 256, 0, stream>>>(hist, 49156);
    code_t_kernel<<<128, 256, 0, stream>>>(tanhpt, code_t);
    hist_kernel<<<128, 256, 0, stream>>>(code_t, hist);
    score_kernel<<<32, 256, 0, stream>>>(hist, code_n, score, shist);
    select_kernel<<<2, 256, 0, stream>>>(shist, selmeta);
    build_sids_kernel<<<2, 256, 0, stream>>>(score, selmeta, sids);
    tanhpn_kernel<<<1024, 256, 0, stream>>>(projn, sids, tanhpn);

    // ---- logits (bf16, ws; f32 acc), both chunks in one launch ----
    logits_kernel<<<dim3(16, 16, 2), 256, 0, stream>>>(normed, W1, sids, b1, logits);

    // ---- triplet (reads d_out scratch; must precede final writes) ----
    topk_kernel<<<2048, 256, 0, stream>>>(logits, tanhpt, tanhpn, trip);
    trip_mean_kernel<<<1, 256, 0, stream>>>(trip, out);

    // ---- final FFN output (overwrites d_out matrix) ----
    copy_int_kernel<<<8, 256, 0, stream>>>(sids, sids_ws, 2048);
    out_kernel<<<dim3(16, 16, 2), 256, 0, stream>>>(logits, W2, sids_ws, b2w, attnO, out);
}

// Round 11
// 1613.969 us; speedup vs baseline: 1.9289x; 1.2451x over previous
//
#include <hip/hip_runtime.h>
#include <hip/hip_bf16.h>
#include <math.h>

typedef __hip_bfloat16 bf16;
__device__ __forceinline__ float b2f(bf16 x) { return __bfloat162float(x); }

#define LN_EPS 1e-12f
#define NEG_INF (-3.0e38f)

__global__ __launch_bounds__(256)
void copy_int_kernel(const int* __restrict__ src, int* __restrict__ dst, int n)
{
    int i = blockIdx.x * 256 + threadIdx.x;
    if (i < n) dst[i] = src[i];
}

// ============================ LayerNorm (f32 -> f32, f64 stats) ============================
__global__ __launch_bounds__(256)
void ln_kernel(const float* __restrict__ in, const float* __restrict__ g,
               const float* __restrict__ b, float* __restrict__ out)
{
    const int D = 1024;
    int row = blockIdx.x, tid = threadIdx.x;
    size_t base = (size_t)row * D + tid * 4;
    float x[4];
    #pragma unroll
    for (int i = 0; i < 4; ++i) x[i] = in[base + i];
    double s  = (double)x[0] + x[1] + x[2] + x[3];
    double sq = (double)x[0]*x[0] + (double)x[1]*x[1] + (double)x[2]*x[2] + (double)x[3]*x[3];
    __shared__ double rs[256], rq[256];
    rs[tid] = s; rq[tid] = sq;
    __syncthreads();
    for (int o = 128; o > 0; o >>= 1) {
        if (tid < o) { rs[tid] += rs[tid + o]; rq[tid] += rq[tid + o]; }
        __syncthreads();
    }
    double mean = rs[0] * (1.0 / D);
    double var  = rq[0] * (1.0 / D) - mean * mean;
    double inv  = rsqrt(var + (double)LN_EPS);
    #pragma unroll
    for (int i = 0; i < 4; ++i) {
        int col = tid * 4 + i;
        out[base + i] = (float)(((double)x[i] - mean) * inv * (double)g[col] + (double)b[col]);
    }
}

// ============================ generic NT GEMM (f32 storage, templated accumulator) =========
#define BM 64
#define BN 64
#define BK 16
template<typename ACC>
__global__ __launch_bounds__(256)
void gemm_nt_t(const float* __restrict__ A, int lda,
               const float* __restrict__ B, int ldb,
               const int* __restrict__ gatherB,
               const float* __restrict__ bias,
               const float* __restrict__ residual,
               void* __restrict__ out_, int oBf, int ldc, int mode,
               int M, int N, int Kd)
{
    __shared__ __align__(16) float As[BK][BM + 4];
    __shared__ __align__(16) float Bs[BK][BN + 4];
    int tid = threadIdx.x;
    int bm = blockIdx.y * BM, bn = blockIdx.x * BN;
    int lm  = tid >> 2;
    int lk4 = (tid & 3) * 4;
    int tm = (tid >> 4) * 4, tn = (tid & 15) * 4;
    ACC acc[4][4] = {};
    for (int k0 = 0; k0 < Kd; k0 += BK) {
        {
            const float* p = A + (size_t)(bm + lm) * lda + k0 + lk4;
            #pragma unroll
            for (int i = 0; i < 4; ++i) As[lk4 + i][lm] = p[i];
        }
        {
            int r = bn + lm;
            if (gatherB) r = gatherB[r] & 4095;
            const float* p = B + (size_t)r * ldb + k0 + lk4;
            #pragma unroll
            for (int i = 0; i < 4; ++i) Bs[lk4 + i][lm] = p[i];
        }
        __syncthreads();
        #pragma unroll
        for (int k = 0; k < BK; ++k) {
            float4 av = *(const float4*)&As[k][tm];
            float4 bw = *(const float4*)&Bs[k][tn];
            float avx[4] = {av.x, av.y, av.z, av.w};
            float bwx[4] = {bw.x, bw.y, bw.z, bw.w};
            #pragma unroll
            for (int i = 0; i < 4; ++i)
                #pragma unroll
                for (int j = 0; j < 4; ++j)
                    acc[i][j] += (ACC)avx[i] * (ACC)bwx[j];
        }
        __syncthreads();
    }
    #pragma unroll
    for (int i = 0; i < 4; ++i) {
        int m = bm + tm + i;
        #pragma unroll
        for (int j = 0; j < 4; ++j) {
            int n = bn + tn + j;
            ACC v = acc[i][j];
            if (bias) { int bi2 = gatherB ? (gatherB[n] & 4095) : n; v += (ACC)bias[bi2]; }
            if (residual) v += (ACC)residual[(size_t)m * ldc + n];
            size_t idx;
            if (mode == 0)      idx = (size_t)m * ldc + n;
            else if (mode == 1) idx = (size_t)(n >> 6) * ((size_t)M * 64) + (size_t)m * 64 + (n & 63);
            else                idx = (size_t)(n >> 3) * ((size_t)M * 8) + (size_t)m * 8 + (n & 7);
            if (oBf) ((bf16*)out_)[idx] = __float2bfloat16((float)v);
            else     ((float*)out_)[idx] = (float)v;
        }
    }
}

// ============================ QKV fused (z selects Q/K/V), f32 acc, mode1 out ==============
__global__ __launch_bounds__(256)
void qkv_kernel(const float* __restrict__ A,
                const float* __restrict__ Wq, const float* __restrict__ Wk, const float* __restrict__ Wv,
                const float* __restrict__ bq, const float* __restrict__ bk, const float* __restrict__ bv,
                float* __restrict__ qo, float* __restrict__ ko, float* __restrict__ vo)
{
    const int lda = 1024, ldb = 1024, Kd = 1024, M = 2048;
    const float* B    = (blockIdx.z == 0) ? Wq : (blockIdx.z == 1) ? Wk : Wv;
    const float* bias = (blockIdx.z == 0) ? bq : (blockIdx.z == 1) ? bk : bv;
    float* out        = (blockIdx.z == 0) ? qo : (blockIdx.z == 1) ? ko : vo;
    __shared__ __align__(16) float As[BK][BM + 4];
    __shared__ __align__(16) float Bs[BK][BN + 4];
    int tid = threadIdx.x;
    int bm = blockIdx.y * BM, bn = blockIdx.x * BN;
    int lm  = tid >> 2;
    int lk4 = (tid & 3) * 4;
    int tm = (tid >> 4) * 4, tn = (tid & 15) * 4;
    float acc[4][4] = {};
    for (int k0 = 0; k0 < Kd; k0 += BK) {
        {
            const float* p = A + (size_t)(bm + lm) * lda + k0 + lk4;
            #pragma unroll
            for (int i = 0; i < 4; ++i) As[lk4 + i][lm] = p[i];
        }
        {
            const float* p = B + (size_t)(bn + lm) * ldb + k0 + lk4;
            #pragma unroll
            for (int i = 0; i < 4; ++i) Bs[lk4 + i][lm] = p[i];
        }
        __syncthreads();
        #pragma unroll
        for (int k = 0; k < BK; ++k) {
            float4 av = *(const float4*)&As[k][tm];
            float4 bw = *(const float4*)&Bs[k][tn];
            float avx[4] = {av.x, av.y, av.z, av.w};
            float bwx[4] = {bw.x, bw.y, bw.z, bw.w};
            #pragma unroll
            for (int i = 0; i < 4; ++i)
                #pragma unroll
                for (int j = 0; j < 4; ++j)
                    acc[i][j] += avx[i] * bwx[j];
        }
        __syncthreads();
    }
    #pragma unroll
    for (int i = 0; i < 4; ++i) {
        int m = bm + tm + i;
        #pragma unroll
        for (int j = 0; j < 4; ++j) {
            int n = bn + tn + j;
            float v = acc[i][j] + bias[n];
            size_t idx = (size_t)(n >> 6) * ((size_t)M * 64) + (size_t)m * 64 + (n & 63);
            out[idx] = v;
        }
    }
}

// ============================ logits GEMM (z = chunk), f32 acc, bf16 out ===================
__global__ __launch_bounds__(256)
void logits_kernel(const float* __restrict__ normed, const float* __restrict__ W1,
                   const int* __restrict__ sids, const float* __restrict__ b1,
                   bf16* __restrict__ logits)
{
    const int lda = 1024, ldb = 1024, ldc = 1024, Kd = 1024;
    size_t chOff = (size_t)blockIdx.z * 1048576;
    const float* A = normed + chOff;
    const int* gk = sids + blockIdx.z * 1024;
    bf16* out = logits + chOff;
    __shared__ __align__(16) float As[BK][BM + 4];
    __shared__ __align__(16) float Bs[BK][BN + 4];
    int tid = threadIdx.x;
    int bm = blockIdx.y * BM, bn = blockIdx.x * BN;
    int lm  = tid >> 2;
    int lk4 = (tid & 3) * 4;
    int tm = (tid >> 4) * 4, tn = (tid & 15) * 4;
    float acc[4][4] = {};
    for (int k0 = 0; k0 < Kd; k0 += BK) {
        {
            const float* p = A + (size_t)(bm + lm) * lda + k0 + lk4;
            #pragma unroll
            for (int i = 0; i < 4; ++i) As[lk4 + i][lm] = p[i];
        }
        {
            int r = gk[bn + lm] & 4095;
            const float* p = W1 + (size_t)r * ldb + k0 + lk4;
            #pragma unroll
            for (int i = 0; i < 4; ++i) Bs[lk4 + i][lm] = p[i];
        }
        __syncthreads();
        #pragma unroll
        for (int k = 0; k < BK; ++k) {
            float4 av = *(const float4*)&As[k][tm];
            float4 bw = *(const float4*)&Bs[k][tn];
            float avx[4] = {av.x, av.y, av.z, av.w};
            float bwx[4] = {bw.x, bw.y, bw.z, bw.w};
            #pragma unroll
            for (int i = 0; i < 4; ++i)
                #pragma unroll
                for (int j = 0; j < 4; ++j)
                    acc[i][j] += avx[i] * bwx[j];
        }
        __syncthreads();
    }
    #pragma unroll
    for (int i = 0; i < 4; ++i) {
        int m = bm + tm + i;
        #pragma unroll
        for (int j = 0; j < 4; ++j) {
            int n = bn + tn + j;
            float v = acc[i][j] + b1[gk[n] & 4095];
            out[(size_t)m * ldc + n] = __float2bfloat16(v);
        }
    }
}

// ==== output GEMM (z = chunk): gelu(logits) @ W2[sids] + b2 + attnO -> d_out ====
__global__ __launch_bounds__(256)
void out_kernel(const bf16* __restrict__ logits, const float* __restrict__ W2,
                const int* __restrict__ sids, const float* __restrict__ b2w,
                const float* __restrict__ attnO, float* __restrict__ out)
{
    const int lda = 1024, ldb = 1024, ldc = 1024, Kd = 1024;
    size_t chOff = (size_t)blockIdx.z * 1048576;
    const bf16* A = logits + chOff;
    const int* gk = sids + blockIdx.z * 1024;
    const float* residual = attnO + chOff;
    __shared__ __align__(16) float As[BK][BM + 4];
    __shared__ __align__(16) float Bs[BK][BN + 4];
    int tid = threadIdx.x;
    int bm = blockIdx.y * BM, bn = blockIdx.x * BN;
    int lm  = tid >> 2;
    int lk4 = (tid & 3) * 4;
    int bkr = tid >> 4;
    int bn4 = (tid & 15) * 4;
    int tm = (tid >> 4) * 4, tn = (tid & 15) * 4;
    float acc[4][4] = {};
    for (int k0 = 0; k0 < Kd; k0 += BK) {
        {
            const bf16* p = A + (size_t)(bm + lm) * lda + k0 + lk4;
            #pragma unroll
            for (int i = 0; i < 4; ++i) {
                float x = b2f(p[i]);
                As[lk4 + i][lm] = 0.5f * x * (1.0f + erff(x * 0.70710678118654752f));
            }
        }
        {
            int r = gk[k0 + bkr] & 4095;
            const float* q = W2 + (size_t)r * ldb + bn + bn4;
            #pragma unroll
            for (int i = 0; i < 4; ++i) Bs[bkr][bn4 + i] = q[i];
        }
        __syncthreads();
        #pragma unroll
        for (int k = 0; k < BK; ++k) {
            float4 av = *(const float4*)&As[k][tm];
            float4 bw = *(const float4*)&Bs[k][tn];
            float avx[4] = {av.x, av.y, av.z, av.w};
            float bwx[4] = {bw.x, bw.y, bw.z, bw.w};
            #pragma unroll
            for (int i = 0; i < 4; ++i)
                #pragma unroll
                for (int j = 0; j < 4; ++j)
                    acc[i][j] += avx[i] * bwx[j];
        }
        __syncthreads();
    }
    #pragma unroll
    for (int i = 0; i < 4; ++i) {
        int m = bm + tm + i;
        #pragma unroll
        for (int j = 0; j < 4; ++j) {
            int n = bn + tn + j;
            float v = acc[i][j] + b2w[n] + residual[(size_t)m * ldc + n];
            out[chOff + (size_t)m * ldc + n] = v;
        }
    }
}

// ============================ flash attention v4 (all f32, no max-shift) ===================
// amask>=0 guarantees scores <= ~O(1); exp never overflows; masked cols -> exp(-1000)=0.
// LDS stride 76 floats: 16B-aligned rows AND conflict-free (19 coprime 32).
__global__ __launch_bounds__(256)
void flash_kernel(const float* __restrict__ q, const float* __restrict__ k,
                  const float* __restrict__ v, const float* __restrict__ amask,
                  float* __restrict__ ctx, int hbase)
{
    int qt = blockIdx.x, hl = blockIdx.y, tid = threadIdx.x;
    int ty = tid >> 4, tx = tid & 15;
    int r0 = ty * 2;
    __shared__ __align__(16) float Qs[32][76];
    __shared__ __align__(16) float KVs[64][76];
    __shared__ __align__(16) float St[32][76];
    __shared__ float lrow[32], msk[64];
    const float* qh = q + (size_t)hl * 131072 + (size_t)qt * 2048;
    #pragma unroll
    for (int rep = 0; rep < 2; ++rep) {
        int lin = rep * 1024 + tid * 4;
        int r = lin >> 6, c = lin & 63;
        float4 u = *(const float4*)(qh + r * 64 + c);
        Qs[r][c] = u.x; Qs[r][c+1] = u.y; Qs[r][c+2] = u.z; Qs[r][c+3] = u.w;
    }
    if (tid < 32) lrow[tid] = 0.0f;
    float o0[4] = {}, o1[4] = {};
    for (int kt = 0; kt < 32; ++kt) {
        const float* kh = k + (size_t)hl * 131072 + (size_t)kt * 4096;
        const float* vh = v + (size_t)hl * 131072 + (size_t)kt * 4096;
        #pragma unroll
        for (int rep = 0; rep < 4; ++rep) {
            int lin = rep * 1024 + tid * 4;
            int r = lin >> 6, c = lin & 63;
            float4 u = *(const float4*)(kh + r * 64 + c);
            KVs[r][c] = u.x; KVs[r][c+1] = u.y; KVs[r][c+2] = u.z; KVs[r][c+3] = u.w;
        }
        if (tid < 64) msk[tid] = 1000.0f * (1.0f - amask[kt * 64 + tid]);
        __syncthreads();
        // scores (f32), lane owns cols tx+16j
        float sc0[4] = {}, sc1[4] = {};
        #pragma unroll 4
        for (int d = 0; d < 64; d += 4) {
            float4 q0 = *(const float4*)&Qs[r0][d];
            float4 q1 = *(const float4*)&Qs[r0 + 1][d];
            #pragma unroll
            for (int j = 0; j < 4; ++j) {
                float4 kv = *(const float4*)&KVs[tx + 16 * j][d];
                sc0[j] += q0.x * kv.x + q0.y * kv.y + q0.z * kv.z + q0.w * kv.w;
                sc1[j] += q1.x * kv.x + q1.y * kv.y + q1.z * kv.z + q1.w * kv.w;
            }
        }
        __syncthreads();   // K reads done -> KVs free for V
        // P = exp(s) without max shift; accumulate l
        float sum0 = 0.0f, sum1 = 0.0f;
        #pragma unroll
        for (int j = 0; j < 4; ++j) {
            float p0 = expf(sc0[j] * 0.125f - msk[tx + 16 * j]);
            float p1 = expf(sc1[j] * 0.125f - msk[tx + 16 * j]);
            St[r0][tx + 16 * j] = p0; St[r0 + 1][tx + 16 * j] = p1;
            sum0 += p0; sum1 += p1;
        }
        #pragma unroll
        for (int off = 1; off < 16; off <<= 1) {
            sum0 += __shfl_xor(sum0, off, 16);
            sum1 += __shfl_xor(sum1, off, 16);
        }
        if (tx == 0) { lrow[r0] += sum0; lrow[r0 + 1] += sum1; }
        // load V into KVs
        #pragma unroll
        for (int rep = 0; rep < 4; ++rep) {
            int lin = rep * 1024 + tid * 4;
            int r = lin >> 6, c = lin & 63;
            float4 w = *(const float4*)(vh + r * 64 + c);
            KVs[r][c] = w.x; KVs[r][c+1] = w.y; KVs[r][c+2] = w.z; KVs[r][c+3] = w.w;
        }
        __syncthreads();   // V + St ready
        // O += P V   (f32)
        for (int j2 = 0; j2 < 64; j2 += 4) {
            float4 p0v = *(const float4*)&St[r0][j2];
            float4 p1v = *(const float4*)&St[r0 + 1][j2];
            float p0a[4] = {p0v.x, p0v.y, p0v.z, p0v.w};
            float p1a[4] = {p1v.x, p1v.y, p1v.z, p1v.w};
            #pragma unroll
            for (int e = 0; e < 4; ++e) {
                float4 vv = *(const float4*)&KVs[j2 + e][tx * 4];
                o0[0] += p0a[e] * vv.x; o0[1] += p0a[e] * vv.y; o0[2] += p0a[e] * vv.z; o0[3] += p0a[e] * vv.w;
                o1[0] += p1a[e] * vv.x; o1[1] += p1a[e] * vv.y; o1[2] += p1a[e] * vv.z; o1[3] += p1a[e] * vv.w;
            }
        }
        __syncthreads();   // protect KVs/St for next kt
    }
    float inv0 = 1.0f / lrow[r0], inv1 = 1.0f / lrow[r0 + 1];
    size_t base0 = (size_t)(qt * 32 + r0) * 1024 + (hbase + hl) * 64 + tx * 4;
    size_t base1 = base0 + 1024;
    #pragma unroll
    for (int j = 0; j < 4; ++j) {
        ctx[base0 + j] = o0[j] * inv0;
        ctx[base1 + j] = o1[j] * inv1;
    }
}

// ============================ hashing / routing ============================
// also zeroes hist/score/shist (49156 ints) for the later kernels
__global__ __launch_bounds__(256)
void code_n_kernel(const float* __restrict__ projn, int* __restrict__ code_n,
                   int* __restrict__ zero_base)
{
    int i = blockIdx.x * 256 + threadIdx.x;
    const float* p = projn + (size_t)i * 8;
    int code = 0;
    #pragma unroll
    for (int k = 0; k < 8; ++k) code |= ((int)(p[k] > 0.0f)) << k;
    code_n[i] = code;
    if (i < 49156) zero_base[i] = 0;
}

__global__ __launch_bounds__(256)
void code_t_kernel(float* __restrict__ pt, int* __restrict__ code_t)
{
    int i = blockIdx.x * 256 + threadIdx.x;
    int t = i >> 4, l = i & 15;
    float* p = pt + (size_t)t * 128 + l * 8;
    int code = 0;
    #pragma unroll
    for (int k = 0; k < 8; ++k) {
        float v = p[k];
        code |= ((int)(v > 0.0f)) << k;
        p[k] = tanhf(v);
    }
    code_t[l * 2048 + t] = code;
}

__global__ __launch_bounds__(256)
void hist_kernel(const int* __restrict__ code_t, int* __restrict__ hist)
{
    int i = blockIdx.x * 256 + threadIdx.x;
    int c = i >> 14, l = (i >> 10) & 15, t = i & 1023;
    int code = code_t[l * 2048 + c * 1024 + t] & 255;
    atomicAdd(&hist[(c * 16 + l) * 256 + code], 1);
}

__global__ __launch_bounds__(256)
void score_kernel(const int* __restrict__ hist, const int* __restrict__ code_n,
                  int* __restrict__ score, int* __restrict__ shist)
{
    int i = blockIdx.x * 256 + threadIdx.x;
    int c = i >> 12, n = i & 4095;
    int s = 0;
    #pragma unroll
    for (int l = 0; l < 16; ++l) s += hist[(c * 16 + l) * 256 + (code_n[l * 4096 + n] & 255)];
    if (s < 0) s = 0; if (s > 16384) s = 16384;
    score[c * 4096 + n] = s;
    atomicAdd(&shist[c * 16385 + s], 1);
}

__global__ __launch_bounds__(256)
void select_kernel(const int* __restrict__ shist, int* __restrict__ selmeta)
{
    int c = blockIdx.x, tid = threadIdx.x;
    const int* bins = shist + c * 16385;
    __shared__ int psum[256];
    int s = 0;
    for (int i = 0; i < 64; ++i) s += bins[tid * 64 + i];
    if (tid == 255) s += bins[16384];
    psum[tid] = s;
    __syncthreads();
    if (tid == 0) {
        int cum = 0, sstar = 0, cntge = 0;
        for (int t = 255; t >= 0; --t) {
            if (cum + psum[t] >= 1024) {
                int hi = (t == 255) ? 16384 : t * 64 + 63;
                for (int b = hi; b >= t * 64; --b) {
                    cum += bins[b];
                    if (cum >= 1024) { sstar = b; cntge = cum; break; }
                }
                break;
            }
            cum += psum[t];
        }
        selmeta[c * 2]     = sstar;
        selmeta[c * 2 + 1] = 1024 - (cntge - bins[sstar]);
    }
}

__global__ __launch_bounds__(256)
void build_sids_kernel(const int* __restrict__ score, const int* __restrict__ selmeta,
                       int* __restrict__ sids)
{
    int c = blockIdx.x, tid = threadIdx.x;
    const int* sc2 = score + c * 4096;
    int sstar = selmeta[c * 2], need_eq = selmeta[c * 2 + 1];
    __shared__ int scan[256];
    int base = tid * 16;
    int mysc[16];
    int eqc = 0;
    #pragma unroll
    for (int i = 0; i < 16; ++i) { mysc[i] = sc2[base + i]; eqc += (mysc[i] == sstar); }
    scan[tid] = eqc; __syncthreads();
    for (int o = 1; o < 256; o <<= 1) {
        int v = (tid >= o) ? scan[tid - o] : 0;
        __syncthreads();
        scan[tid] += v;
        __syncthreads();
    }
    int eqr = scan[tid] - eqc;
    __syncthreads();
    int selc = 0; unsigned flags = 0;
    #pragma unroll
    for (int i = 0; i < 16; ++i) {
        bool sel = false;
        if (mysc[i] > sstar) sel = true;
        else if (mysc[i] == sstar) { sel = (eqr < need_eq); eqr++; }
        if (sel) { flags |= (1u << i); selc++; }
    }
    scan[tid] = selc; __syncthreads();
    for (int o = 1; o < 256; o <<= 1) {
        int v = (tid >= o) ? scan[tid - o] : 0;
        __syncthreads();
        scan[tid] += v;
        __syncthreads();
    }
    int pos = scan[tid] - selc;
    #pragma unroll
    for (int i = 0; i < 16; ++i)
        if (flags & (1u << i)) { if (pos < 1024) sids[c * 1024 + pos] = base + i; pos++; }
}

__global__ __launch_bounds__(256)
void tanhpn_kernel(const float* __restrict__ projn, const int* __restrict__ sids,
                   float* __restrict__ tanhpn)
{
    int i = blockIdx.x * 256 + threadIdx.x;
    int c = i >> 17;
    int r = i & 131071;
    int s = r >> 7, j = r & 127;
    int l = j >> 3, k = j & 7;
    int n = sids[c * 1024 + s] & 4095;
    tanhpn[(size_t)c * 131072 + (size_t)s * 128 + j] = tanhf(projn[(size_t)l * 32768 + (size_t)n * 8 + k]);
}

// ============================ per-row top-64 pos/neg + triplet (shfl argmax) ===============
__global__ __launch_bounds__(256)
void topk_kernel(const bf16* __restrict__ logits, const float* __restrict__ tanhpt,
                 const float* __restrict__ tanhpn, float* __restrict__ trip)
{
    int t = blockIdx.x;
    int c = t >> 10, tid = threadIdx.x;
    __shared__ float agr[1024];
    __shared__ float qrow[128];
    __shared__ float wv_[4];
    __shared__ int   wi_[4];
    __shared__ int   bcast;
    if (tid < 128) qrow[tid] = tanhpt[(size_t)t * 128 + tid];
    __syncthreads();
    for (int s = tid; s < 1024; s += 256) {
        const float* pn = tanhpn + ((size_t)c * 1024 + s) * 128;
        float acc = 0.0f;
        #pragma unroll 8
        for (int d = 0; d < 128; ++d) acc += qrow[d] * pn[d];
        agr[s] = acc * (1.0f / 128.0f);
    }
    const bf16* lrow = logits + (size_t)t * 1024;
    float base[4];
    #pragma unroll
    for (int r = 0; r < 4; ++r) base[r] = b2f(lrow[r * 256 + tid]);
    __syncthreads();
    float mres[2];
    for (int p = 0; p < 2; ++p) {
        float mv[4];
        #pragma unroll
        for (int r = 0; r < 4; ++r) mv[r] = p ? -base[r] : base[r];
        float asum = 0.0f;
        for (int it = 0; it < 64; ++it) {
            float bv = mv[0]; int bi = tid;
            #pragma unroll
            for (int r = 1; r < 4; ++r)
                if (mv[r] > bv) { bv = mv[r]; bi = r * 256 + tid; }
            #pragma unroll
            for (int off = 1; off < 64; off <<= 1) {
                float ov = __shfl_xor(bv, off, 64);
                int   oi = __shfl_xor(bi, off, 64);
                if (ov > bv || (ov == bv && oi < bi)) { bv = ov; bi = oi; }
            }
            if ((tid & 63) == 0) { wv_[tid >> 6] = bv; wi_[tid >> 6] = bi; }
            __syncthreads();
            if (tid == 0) {
                float fv = wv_[0]; int fi = wi_[0];
                #pragma unroll
                for (int w = 1; w < 4; ++w) {
                    float ov = wv_[w]; int oi = wi_[w];
                    if (ov > fv || (ov == fv && oi < fi)) { fv = ov; fi = oi; }
                }
                asum += agr[fi];
                bcast = fi;
            }
            __syncthreads();
            int w = bcast;
            if ((w & 255) == tid) mv[w >> 8] = NEG_INF;
        }
        mres[p] = asum * (1.0f / 64.0f);
    }
    if (tid == 0) {
        float v = mres[1] - mres[0] + 0.5f;
        trip[t] = v > 0.0f ? v : 0.0f;
    }
}

__global__ __launch_bounds__(256)
void trip_mean_kernel(const float* __restrict__ trip, float* __restrict__ out)
{
    int tid = threadIdx.x;
    float s = 0.0f;
    for (int i = tid; i < 2048; i += 256) s += trip[i];
    __shared__ float rs[256];
    rs[tid] = s; __syncthreads();
    for (int o = 128; o > 0; o >>= 1) { if (tid < o) rs[tid] += rs[tid + o]; __syncthreads(); }
    if (tid == 0) out[2097152] = rs[0] * (1.0f / 2048.0f);
}

// ============================ launch ============================
extern "C" void kernel_launch(void* const* d_in, const int* in_sizes, int n_in,
                              void* d_out, int out_size, void* d_ws, size_t ws_size,
                              hipStream_t stream)
{
    const float* hidden = (const float*)d_in[0];
    const float* amask  = (const float*)d_in[1];
    const float* ln1g   = (const float*)d_in[2];
    const float* ln1b   = (const float*)d_in[3];
    const float* Wq     = (const float*)d_in[4];
    const float* bq     = (const float*)d_in[5];
    const float* Wk     = (const float*)d_in[6];
    const float* bk     = (const float*)d_in[7];
    const float* Wv     = (const float*)d_in[8];
    const float* bv     = (const float*)d_in[9];
    const float* Wo     = (const float*)d_in[10];
    const float* bo     = (const float*)d_in[11];
    const float* ln2g   = (const float*)d_in[12];
    const float* ln2b   = (const float*)d_in[13];
    const float* W1     = (const float*)d_in[14];
    const float* b1     = (const float*)d_in[15];
    const float* Whash  = (const float*)d_in[16];
    const float* W2     = (const float*)d_in[17];
    const float* b2w    = (const float*)d_in[18];
    float* out = (float*)d_out;
    float* ws  = (float*)d_ws;
    const size_t MB = 1024 * 1024;
    if (ws_size < 20 * MB) return;

    // ---- ws layout (floats), 20 MB ----
    float* xln    = ws;                 // [0,8MB)
    float* qg     = ws + 2097152;       // [8,12MB)
    float* kg     = ws + 3145728;       // [12,16MB)
    float* vg     = ws + 4194304;       // [16,20MB)
    float* attnO  = ws + 2097152;       // [8,16MB) after flash
    float* normed = ws;                 // [0,8MB)
    bf16*  logits = (bf16*)(ws + 4194304); // [16,20MB)
    int*   sids_ws = (int*)ws;          // [0,8KB) after normed dead

    // ---- d_out scratch layout (floats) ----
    float* ctx    = out;
    float* projn  = out;
    float* tanhpt = out + 524288;
    float* tanhpn = out + 786432;
    int*   dints  = (int*)out + 1048576;
    int*   code_n = dints;
    int*   code_t = dints + 65536;
    int*   hist   = dints + 98304;
    int*   score  = dints + 106496;
    int*   shist  = dints + 114688;
    int*   selmeta= dints + 147460;
    int*   sids   = dints + 147464;
    float* trip   = (float*)(dints + 149512);

    // ---- attention (2 head-groups of 8; f32) ----
    ln_kernel<<<2048, 256, 0, stream>>>(hidden, ln1g, ln1b, xln);
    for (int g = 0; g < 2; ++g) {
        const size_t wOff = (size_t)g * 512 * 1024;
        qkv_kernel<<<dim3(8, 32, 3), 256, 0, stream>>>(xln, Wq + wOff, Wk + wOff, Wv + wOff,
                                                       bq + g * 512, bk + g * 512, bv + g * 512,
                                                       qg, kg, vg);
        flash_kernel<<<dim3(64, 8), 256, 0, stream>>>(qg, kg, vg, amask, ctx, g * 8);
    }
    gemm_nt_t<float><<<dim3(16, 32), 256, 0, stream>>>(ctx, 1024, Wo, 1024, nullptr, bo, hidden, attnO, 0, 1024, 0, 2048, 1024, 1024);

    // ---- FFN routing (hash projections stay f64-accumulated: sign-critical) ----
    ln_kernel<<<2048, 256, 0, stream>>>(attnO, ln2g, ln2b, normed);
    gemm_nt_t<double><<<dim3(2, 64), 256, 0, stream>>>(W1, 1024, Whash, 1024, nullptr, nullptr, nullptr, projn, 0, 0, 3, 4096, 128, 1024);
    code_n_kernel<<<256, 256, 0, stream>>>(projn, code_n, hist);
    gemm_nt_t<double><<<dim3(2, 32), 256, 0, stream>>>(normed, 1024, Whash, 1024, nullptr, nullptr, nullptr, tanhpt, 0, 128, 0, 2048, 128, 1024);
    code_t_kernel<<<128, 256, 0, stream>>>(tanhpt, code_t);
    hist_kernel<<<128, 256, 0, stream>>>(code_t, hist);
    score_kernel<<<32, 256, 0, stream>>>(hist, code_n, score, shist);
    select_kernel<<<2, 256, 0, stream>>>(shist, selmeta);
    build_sids_kernel<<<2, 256, 0, stream>>>(score, selmeta, sids);
    tanhpn_kernel<<<1024, 256, 0, stream>>>(projn, sids, tanhpn);

    // ---- logits (bf16, ws; f32 acc), both chunks in one launch ----
    logits_kernel<<<dim3(16, 16, 2), 256, 0, stream>>>(normed, W1, sids, b1, logits);

    // ---- triplet (reads d_out scratch; must precede final writes) ----
    topk_kernel<<<2048, 256, 0, stream>>>(logits, tanhpt, tanhpn, trip);
    trip_mean_kernel<<<1, 256, 0, stream>>>(trip, out);

    // ---- final FFN output (overwrites d_out matrix) ----
    copy_int_kernel<<<8, 256, 0, stream>>>(sids, sids_ws, 2048);
    out_kernel<<<dim3(16, 16, 2), 256, 0, stream>>>(logits, W2, sids_ws, b2w, attnO, out);
}

// Round 12
// 1501.331 us; speedup vs baseline: 2.0736x; 1.0750x over previous
//
#include <hip/hip_runtime.h>
#include <hip/hip_bf16.h>
#include <math.h>

typedef __hip_bfloat16 bf16;
__device__ __forceinline__ float b2f(bf16 x) { return __bfloat162float(x); }
// order-preserving float->uint key (larger float => larger key)
__device__ __forceinline__ unsigned fkey(float f) {
    unsigned u = __float_as_uint(f);
    return (u & 0x80000000u) ? ~u : (u | 0x80000000u);
}

#define LN_EPS 1e-12f
#define NEG_INF (-3.0e38f)

__global__ __launch_bounds__(256)
void copy_int_kernel(const int* __restrict__ src, int* __restrict__ dst, int n)
{
    int i = blockIdx.x * 256 + threadIdx.x;
    if (i < n) dst[i] = src[i];
}

// ============================ LayerNorm (f32 -> f32, f64 stats) ============================
__global__ __launch_bounds__(256)
void ln_kernel(const float* __restrict__ in, const float* __restrict__ g,
               const float* __restrict__ b, float* __restrict__ out)
{
    const int D = 1024;
    int row = blockIdx.x, tid = threadIdx.x;
    size_t base = (size_t)row * D + tid * 4;
    float x[4];
    #pragma unroll
    for (int i = 0; i < 4; ++i) x[i] = in[base + i];
    double s  = (double)x[0] + x[1] + x[2] + x[3];
    double sq = (double)x[0]*x[0] + (double)x[1]*x[1] + (double)x[2]*x[2] + (double)x[3]*x[3];
    __shared__ double rs[256], rq[256];
    rs[tid] = s; rq[tid] = sq;
    __syncthreads();
    for (int o = 128; o > 0; o >>= 1) {
        if (tid < o) { rs[tid] += rs[tid + o]; rq[tid] += rq[tid + o]; }
        __syncthreads();
    }
    double mean = rs[0] * (1.0 / D);
    double var  = rq[0] * (1.0 / D) - mean * mean;
    double inv  = rsqrt(var + (double)LN_EPS);
    #pragma unroll
    for (int i = 0; i < 4; ++i) {
        int col = tid * 4 + i;
        out[base + i] = (float)(((double)x[i] - mean) * inv * (double)g[col] + (double)b[col]);
    }
}

// ============================ generic NT GEMM (f32 storage, templated accumulator) =========
#define BM 64
#define BN 64
#define BK 16
template<typename ACC>
__global__ __launch_bounds__(256)
void gemm_nt_t(const float* __restrict__ A, int lda,
               const float* __restrict__ B, int ldb,
               const int* __restrict__ gatherB,
               const float* __restrict__ bias,
               const float* __restrict__ residual,
               void* __restrict__ out_, int oBf, int ldc, int mode,
               int M, int N, int Kd)
{
    __shared__ __align__(16) float As[BK][BM + 4];
    __shared__ __align__(16) float Bs[BK][BN + 4];
    int tid = threadIdx.x;
    int bm = blockIdx.y * BM, bn = blockIdx.x * BN;
    int lm  = tid >> 2;
    int lk4 = (tid & 3) * 4;
    int tm = (tid >> 4) * 4, tn = (tid & 15) * 4;
    ACC acc[4][4] = {};
    for (int k0 = 0; k0 < Kd; k0 += BK) {
        {
            const float* p = A + (size_t)(bm + lm) * lda + k0 + lk4;
            #pragma unroll
            for (int i = 0; i < 4; ++i) As[lk4 + i][lm] = p[i];
        }
        {
            int r = bn + lm;
            if (gatherB) r = gatherB[r] & 4095;
            const float* p = B + (size_t)r * ldb + k0 + lk4;
            #pragma unroll
            for (int i = 0; i < 4; ++i) Bs[lk4 + i][lm] = p[i];
        }
        __syncthreads();
        #pragma unroll
        for (int k = 0; k < BK; ++k) {
            float4 av = *(const float4*)&As[k][tm];
            float4 bw = *(const float4*)&Bs[k][tn];
            float avx[4] = {av.x, av.y, av.z, av.w};
            float bwx[4] = {bw.x, bw.y, bw.z, bw.w};
            #pragma unroll
            for (int i = 0; i < 4; ++i)
                #pragma unroll
                for (int j = 0; j < 4; ++j)
                    acc[i][j] += (ACC)avx[i] * (ACC)bwx[j];
        }
        __syncthreads();
    }
    #pragma unroll
    for (int i = 0; i < 4; ++i) {
        int m = bm + tm + i;
        #pragma unroll
        for (int j = 0; j < 4; ++j) {
            int n = bn + tn + j;
            ACC v = acc[i][j];
            if (bias) { int bi2 = gatherB ? (gatherB[n] & 4095) : n; v += (ACC)bias[bi2]; }
            if (residual) v += (ACC)residual[(size_t)m * ldc + n];
            size_t idx;
            if (mode == 0)      idx = (size_t)m * ldc + n;
            else if (mode == 1) idx = (size_t)(n >> 6) * ((size_t)M * 64) + (size_t)m * 64 + (n & 63);
            else                idx = (size_t)(n >> 3) * ((size_t)M * 8) + (size_t)m * 8 + (n & 7);
            if (oBf) ((bf16*)out_)[idx] = __float2bfloat16((float)v);
            else     ((float*)out_)[idx] = (float)v;
        }
    }
}

// ============================ QKV fused (z selects Q/K/V), f32 acc, mode1 out ==============
__global__ __launch_bounds__(256)
void qkv_kernel(const float* __restrict__ A,
                const float* __restrict__ Wq, const float* __restrict__ Wk, const float* __restrict__ Wv,
                const float* __restrict__ bq, const float* __restrict__ bk, const float* __restrict__ bv,
                float* __restrict__ qo, float* __restrict__ ko, float* __restrict__ vo)
{
    const int lda = 1024, ldb = 1024, Kd = 1024, M = 2048;
    const float* B    = (blockIdx.z == 0) ? Wq : (blockIdx.z == 1) ? Wk : Wv;
    const float* bias = (blockIdx.z == 0) ? bq : (blockIdx.z == 1) ? bk : bv;
    float* out        = (blockIdx.z == 0) ? qo : (blockIdx.z == 1) ? ko : vo;
    __shared__ __align__(16) float As[BK][BM + 4];
    __shared__ __align__(16) float Bs[BK][BN + 4];
    int tid = threadIdx.x;
    int bm = blockIdx.y * BM, bn = blockIdx.x * BN;
    int lm  = tid >> 2;
    int lk4 = (tid & 3) * 4;
    int tm = (tid >> 4) * 4, tn = (tid & 15) * 4;
    float acc[4][4] = {};
    for (int k0 = 0; k0 < Kd; k0 += BK) {
        {
            const float* p = A + (size_t)(bm + lm) * lda + k0 + lk4;
            #pragma unroll
            for (int i = 0; i < 4; ++i) As[lk4 + i][lm] = p[i];
        }
        {
            const float* p = B + (size_t)(bn + lm) * ldb + k0 + lk4;
            #pragma unroll
            for (int i = 0; i < 4; ++i) Bs[lk4 + i][lm] = p[i];
        }
        __syncthreads();
        #pragma unroll
        for (int k = 0; k < BK; ++k) {
            float4 av = *(const float4*)&As[k][tm];
            float4 bw = *(const float4*)&Bs[k][tn];
            float avx[4] = {av.x, av.y, av.z, av.w};
            float bwx[4] = {bw.x, bw.y, bw.z, bw.w};
            #pragma unroll
            for (int i = 0; i < 4; ++i)
                #pragma unroll
                for (int j = 0; j < 4; ++j)
                    acc[i][j] += avx[i] * bwx[j];
        }
        __syncthreads();
    }
    #pragma unroll
    for (int i = 0; i < 4; ++i) {
        int m = bm + tm + i;
        #pragma unroll
        for (int j = 0; j < 4; ++j) {
            int n = bn + tn + j;
            float v = acc[i][j] + bias[n];
            size_t idx = (size_t)(n >> 6) * ((size_t)M * 64) + (size_t)m * 64 + (n & 63);
            out[idx] = v;
        }
    }
}

// ============================ logits GEMM (z = chunk), f32 acc, bf16 out ===================
__global__ __launch_bounds__(256)
void logits_kernel(const float* __restrict__ normed, const float* __restrict__ W1,
                   const int* __restrict__ sids, const float* __restrict__ b1,
                   bf16* __restrict__ logits)
{
    const int lda = 1024, ldb = 1024, ldc = 1024, Kd = 1024;
    size_t chOff = (size_t)blockIdx.z * 1048576;
    const float* A = normed + chOff;
    const int* gk = sids + blockIdx.z * 1024;
    bf16* out = logits + chOff;
    __shared__ __align__(16) float As[BK][BM + 4];
    __shared__ __align__(16) float Bs[BK][BN + 4];
    int tid = threadIdx.x;
    int bm = blockIdx.y * BM, bn = blockIdx.x * BN;
    int lm  = tid >> 2;
    int lk4 = (tid & 3) * 4;
    int tm = (tid >> 4) * 4, tn = (tid & 15) * 4;
    float acc[4][4] = {};
    for (int k0 = 0; k0 < Kd; k0 += BK) {
        {
            const float* p = A + (size_t)(bm + lm) * lda + k0 + lk4;
            #pragma unroll
            for (int i = 0; i < 4; ++i) As[lk4 + i][lm] = p[i];
        }
        {
            int r = gk[bn + lm] & 4095;
            const float* p = W1 + (size_t)r * ldb + k0 + lk4;
            #pragma unroll
            for (int i = 0; i < 4; ++i) Bs[lk4 + i][lm] = p[i];
        }
        __syncthreads();
        #pragma unroll
        for (int k = 0; k < BK; ++k) {
            float4 av = *(const float4*)&As[k][tm];
            float4 bw = *(const float4*)&Bs[k][tn];
            float avx[4] = {av.x, av.y, av.z, av.w};
            float bwx[4] = {bw.x, bw.y, bw.z, bw.w};
            #pragma unroll
            for (int i = 0; i < 4; ++i)
                #pragma unroll
                for (int j = 0; j < 4; ++j)
                    acc[i][j] += avx[i] * bwx[j];
        }
        __syncthreads();
    }
    #pragma unroll
    for (int i = 0; i < 4; ++i) {
        int m = bm + tm + i;
        #pragma unroll
        for (int j = 0; j < 4; ++j) {
            int n = bn + tn + j;
            float v = acc[i][j] + b1[gk[n] & 4095];
            out[(size_t)m * ldc + n] = __float2bfloat16(v);
        }
    }
}

// ==== output GEMM (z = chunk): gelu(logits) @ W2[sids] + b2 + attnO -> d_out ====
__global__ __launch_bounds__(256)
void out_kernel(const bf16* __restrict__ logits, const float* __restrict__ W2,
                const int* __restrict__ sids, const float* __restrict__ b2w,
                const float* __restrict__ attnO, float* __restrict__ out)
{
    const int lda = 1024, ldb = 1024, ldc = 1024, Kd = 1024;
    size_t chOff = (size_t)blockIdx.z * 1048576;
    const bf16* A = logits + chOff;
    const int* gk = sids + blockIdx.z * 1024;
    const float* residual = attnO + chOff;
    __shared__ __align__(16) float As[BK][BM + 4];
    __shared__ __align__(16) float Bs[BK][BN + 4];
    int tid = threadIdx.x;
    int bm = blockIdx.y * BM, bn = blockIdx.x * BN;
    int lm  = tid >> 2;
    int lk4 = (tid & 3) * 4;
    int bkr = tid >> 4;
    int bn4 = (tid & 15) * 4;
    int tm = (tid >> 4) * 4, tn = (tid & 15) * 4;
    float acc[4][4] = {};
    for (int k0 = 0; k0 < Kd; k0 += BK) {
        {
            const bf16* p = A + (size_t)(bm + lm) * lda + k0 + lk4;
            #pragma unroll
            for (int i = 0; i < 4; ++i) {
                float x = b2f(p[i]);
                As[lk4 + i][lm] = 0.5f * x * (1.0f + erff(x * 0.70710678118654752f));
            }
        }
        {
            int r = gk[k0 + bkr] & 4095;
            const float* q = W2 + (size_t)r * ldb + bn + bn4;
            #pragma unroll
            for (int i = 0; i < 4; ++i) Bs[bkr][bn4 + i] = q[i];
        }
        __syncthreads();
        #pragma unroll
        for (int k = 0; k < BK; ++k) {
            float4 av = *(const float4*)&As[k][tm];
            float4 bw = *(const float4*)&Bs[k][tn];
            float avx[4] = {av.x, av.y, av.z, av.w};
            float bwx[4] = {bw.x, bw.y, bw.z, bw.w};
            #pragma unroll
            for (int i = 0; i < 4; ++i)
                #pragma unroll
                for (int j = 0; j < 4; ++j)
                    acc[i][j] += avx[i] * bwx[j];
        }
        __syncthreads();
    }
    #pragma unroll
    for (int i = 0; i < 4; ++i) {
        int m = bm + tm + i;
        #pragma unroll
        for (int j = 0; j < 4; ++j) {
            int n = bn + tn + j;
            float v = acc[i][j] + b2w[n] + residual[(size_t)m * ldc + n];
            out[chOff + (size_t)m * ldc + n] = v;
        }
    }
}

// ============================ flash attention v4 (all f32, no max-shift) ===================
__global__ __launch_bounds__(256)
void flash_kernel(const float* __restrict__ q, const float* __restrict__ k,
                  const float* __restrict__ v, const float* __restrict__ amask,
                  float* __restrict__ ctx, int hbase)
{
    int qt = blockIdx.x, hl = blockIdx.y, tid = threadIdx.x;
    int ty = tid >> 4, tx = tid & 15;
    int r0 = ty * 2;
    __shared__ __align__(16) float Qs[32][76];
    __shared__ __align__(16) float KVs[64][76];
    __shared__ __align__(16) float St[32][76];
    __shared__ float lrow[32], msk[64];
    const float* qh = q + (size_t)hl * 131072 + (size_t)qt * 2048;
    #pragma unroll
    for (int rep = 0; rep < 2; ++rep) {
        int lin = rep * 1024 + tid * 4;
        int r = lin >> 6, c = lin & 63;
        float4 u = *(const float4*)(qh + r * 64 + c);
        Qs[r][c] = u.x; Qs[r][c+1] = u.y; Qs[r][c+2] = u.z; Qs[r][c+3] = u.w;
    }
    if (tid < 32) lrow[tid] = 0.0f;
    float o0[4] = {}, o1[4] = {};
    for (int kt = 0; kt < 32; ++kt) {
        const float* kh = k + (size_t)hl * 131072 + (size_t)kt * 4096;
        const float* vh = v + (size_t)hl * 131072 + (size_t)kt * 4096;
        #pragma unroll
        for (int rep = 0; rep < 4; ++rep) {
            int lin = rep * 1024 + tid * 4;
            int r = lin >> 6, c = lin & 63;
            float4 u = *(const float4*)(kh + r * 64 + c);
            KVs[r][c] = u.x; KVs[r][c+1] = u.y; KVs[r][c+2] = u.z; KVs[r][c+3] = u.w;
        }
        if (tid < 64) msk[tid] = 1000.0f * (1.0f - amask[kt * 64 + tid]);
        __syncthreads();
        float sc0[4] = {}, sc1[4] = {};
        #pragma unroll 4
        for (int d = 0; d < 64; d += 4) {
            float4 q0 = *(const float4*)&Qs[r0][d];
            float4 q1 = *(const float4*)&Qs[r0 + 1][d];
            #pragma unroll
            for (int j = 0; j < 4; ++j) {
                float4 kv = *(const float4*)&KVs[tx + 16 * j][d];
                sc0[j] += q0.x * kv.x + q0.y * kv.y + q0.z * kv.z + q0.w * kv.w;
                sc1[j] += q1.x * kv.x + q1.y * kv.y + q1.z * kv.z + q1.w * kv.w;
            }
        }
        __syncthreads();
        float sum0 = 0.0f, sum1 = 0.0f;
        #pragma unroll
        for (int j = 0; j < 4; ++j) {
            float p0 = expf(sc0[j] * 0.125f - msk[tx + 16 * j]);
            float p1 = expf(sc1[j] * 0.125f - msk[tx + 16 * j]);
            St[r0][tx + 16 * j] = p0; St[r0 + 1][tx + 16 * j] = p1;
            sum0 += p0; sum1 += p1;
        }
        #pragma unroll
        for (int off = 1; off < 16; off <<= 1) {
            sum0 += __shfl_xor(sum0, off, 16);
            sum1 += __shfl_xor(sum1, off, 16);
        }
        if (tx == 0) { lrow[r0] += sum0; lrow[r0 + 1] += sum1; }
        #pragma unroll
        for (int rep = 0; rep < 4; ++rep) {
            int lin = rep * 1024 + tid * 4;
            int r = lin >> 6, c = lin & 63;
            float4 w = *(const float4*)(vh + r * 64 + c);
            KVs[r][c] = w.x; KVs[r][c+1] = w.y; KVs[r][c+2] = w.z; KVs[r][c+3] = w.w;
        }
        __syncthreads();
        for (int j2 = 0; j2 < 64; j2 += 4) {
            float4 p0v = *(const float4*)&St[r0][j2];
            float4 p1v = *(const float4*)&St[r0 + 1][j2];
            float p0a[4] = {p0v.x, p0v.y, p0v.z, p0v.w};
            float p1a[4] = {p1v.x, p1v.y, p1v.z, p1v.w};
            #pragma unroll
            for (int e = 0; e < 4; ++e) {
                float4 vv = *(const float4*)&KVs[j2 + e][tx * 4];
                o0[0] += p0a[e] * vv.x; o0[1] += p0a[e] * vv.y; o0[2] += p0a[e] * vv.z; o0[3] += p0a[e] * vv.w;
                o1[0] += p1a[e] * vv.x; o1[1] += p1a[e] * vv.y; o1[2] += p1a[e] * vv.z; o1[3] += p1a[e] * vv.w;
            }
        }
        __syncthreads();
    }
    float inv0 = 1.0f / lrow[r0], inv1 = 1.0f / lrow[r0 + 1];
    size_t base0 = (size_t)(qt * 32 + r0) * 1024 + (hbase + hl) * 64 + tx * 4;
    size_t base1 = base0 + 1024;
    #pragma unroll
    for (int j = 0; j < 4; ++j) {
        ctx[base0 + j] = o0[j] * inv0;
        ctx[base1 + j] = o1[j] * inv1;
    }
}

// ============================ hashing / routing ============================
__global__ __launch_bounds__(256)
void code_n_kernel(const float* __restrict__ projn, int* __restrict__ code_n,
                   int* __restrict__ zero_base)
{
    int i = blockIdx.x * 256 + threadIdx.x;
    const float* p = projn + (size_t)i * 8;
    int code = 0;
    #pragma unroll
    for (int k = 0; k < 8; ++k) code |= ((int)(p[k] > 0.0f)) << k;
    code_n[i] = code;
    if (i < 49156) zero_base[i] = 0;
}

__global__ __launch_bounds__(256)
void code_t_kernel(float* __restrict__ pt, int* __restrict__ code_t)
{
    int i = blockIdx.x * 256 + threadIdx.x;
    int t = i >> 4, l = i & 15;
    float* p = pt + (size_t)t * 128 + l * 8;
    int code = 0;
    #pragma unroll
    for (int k = 0; k < 8; ++k) {
        float v = p[k];
        code |= ((int)(v > 0.0f)) << k;
        p[k] = tanhf(v);
    }
    code_t[l * 2048 + t] = code;
}

__global__ __launch_bounds__(256)
void hist_kernel(const int* __restrict__ code_t, int* __restrict__ hist)
{
    int i = blockIdx.x * 256 + threadIdx.x;
    int c = i >> 14, l = (i >> 10) & 15, t = i & 1023;
    int code = code_t[l * 2048 + c * 1024 + t] & 255;
    atomicAdd(&hist[(c * 16 + l) * 256 + code], 1);
}

__global__ __launch_bounds__(256)
void score_kernel(const int* __restrict__ hist, const int* __restrict__ code_n,
                  int* __restrict__ score, int* __restrict__ shist)
{
    int i = blockIdx.x * 256 + threadIdx.x;
    int c = i >> 12, n = i & 4095;
    int s = 0;
    #pragma unroll
    for (int l = 0; l < 16; ++l) s += hist[(c * 16 + l) * 256 + (code_n[l * 4096 + n] & 255)];
    if (s < 0) s = 0; if (s > 16384) s = 16384;
    score[c * 4096 + n] = s;
    atomicAdd(&shist[c * 16385 + s], 1);
}

__global__ __launch_bounds__(256)
void select_kernel(const int* __restrict__ shist, int* __restrict__ selmeta)
{
    int c = blockIdx.x, tid = threadIdx.x;
    const int* bins = shist + c * 16385;
    __shared__ int psum[256];
    int s = 0;
    for (int i = 0; i < 64; ++i) s += bins[tid * 64 + i];
    if (tid == 255) s += bins[16384];
    psum[tid] = s;
    __syncthreads();
    if (tid == 0) {
        int cum = 0, sstar = 0, cntge = 0;
        for (int t = 255; t >= 0; --t) {
            if (cum + psum[t] >= 1024) {
                int hi = (t == 255) ? 16384 : t * 64 + 63;
                for (int b = hi; b >= t * 64; --b) {
                    cum += bins[b];
                    if (cum >= 1024) { sstar = b; cntge = cum; break; }
                }
                break;
            }
            cum += psum[t];
        }
        selmeta[c * 2]     = sstar;
        selmeta[c * 2 + 1] = 1024 - (cntge - bins[sstar]);
    }
}

__global__ __launch_bounds__(256)
void build_sids_kernel(const int* __restrict__ score, const int* __restrict__ selmeta,
                       int* __restrict__ sids)
{
    int c = blockIdx.x, tid = threadIdx.x;
    const int* sc2 = score + c * 4096;
    int sstar = selmeta[c * 2], need_eq = selmeta[c * 2 + 1];
    __shared__ int scan[256];
    int base = tid * 16;
    int mysc[16];
    int eqc = 0;
    #pragma unroll
    for (int i = 0; i < 16; ++i) { mysc[i] = sc2[base + i]; eqc += (mysc[i] == sstar); }
    scan[tid] = eqc; __syncthreads();
    for (int o = 1; o < 256; o <<= 1) {
        int v = (tid >= o) ? scan[tid - o] : 0;
        __syncthreads();
        scan[tid] += v;
        __syncthreads();
    }
    int eqr = scan[tid] - eqc;
    __syncthreads();
    int selc = 0; unsigned flags = 0;
    #pragma unroll
    for (int i = 0; i < 16; ++i) {
        bool sel = false;
        if (mysc[i] > sstar) sel = true;
        else if (mysc[i] == sstar) { sel = (eqr < need_eq); eqr++; }
        if (sel) { flags |= (1u << i); selc++; }
    }
    scan[tid] = selc; __syncthreads();
    for (int o = 1; o < 256; o <<= 1) {
        int v = (tid >= o) ? scan[tid - o] : 0;
        __syncthreads();
        scan[tid] += v;
        __syncthreads();
    }
    int pos = scan[tid] - selc;
    #pragma unroll
    for (int i = 0; i < 16; ++i)
        if (flags & (1u << i)) { if (pos < 1024) sids[c * 1024 + pos] = base + i; pos++; }
}

__global__ __launch_bounds__(256)
void tanhpn_kernel(const float* __restrict__ projn, const int* __restrict__ sids,
                   float* __restrict__ tanhpn)
{
    int i = blockIdx.x * 256 + threadIdx.x;
    int c = i >> 17;
    int r = i & 131071;
    int s = r >> 7, j = r & 127;
    int l = j >> 3, k = j & 7;
    int n = sids[c * 1024 + s] & 4095;
    tanhpn[(size_t)c * 131072 + (size_t)s * 128 + j] = tanhf(projn[(size_t)l * 32768 + (size_t)n * 8 + k]);
}

// ============================ topk v3: radix-select per row ============================
// For each row: exact 64th-largest key via 4-pass byte radix descent, then sum agr over
// the top-64 set (ties -> lowest index, matching jax.lax.top_k). No iterative extraction.
__global__ __launch_bounds__(256)
void topk_kernel(const bf16* __restrict__ logits, const float* __restrict__ tanhpt,
                 const float* __restrict__ tanhpn, float* __restrict__ trip)
{
    int t = blockIdx.x;
    int c = t >> 10, tid = threadIdx.x;
    __shared__ float agr[1024];
    __shared__ float qrow[128];
    __shared__ int hist[256];
    __shared__ int scan[256];
    __shared__ float red[256];
    __shared__ int chosen_s, gsel_s;
    if (tid < 128) qrow[tid] = tanhpt[(size_t)t * 128 + tid];
    __syncthreads();
    for (int s = tid; s < 1024; s += 256) {
        const float* pn = tanhpn + ((size_t)c * 1024 + s) * 128;
        float acc = 0.0f;
        #pragma unroll 8
        for (int d = 0; d < 128; ++d) acc += qrow[d] * pn[d];
        agr[s] = acc * (1.0f / 128.0f);
    }
    const bf16* lrow = logits + (size_t)t * 1024;
    float v[4];
    #pragma unroll
    for (int j = 0; j < 4; ++j) v[j] = b2f(lrow[4 * tid + j]);   // thread owns indices 4t..4t+3
    __syncthreads();   // agr ready
    float mres[2];
    for (int p = 0; p < 2; ++p) {
        unsigned key[4];
        #pragma unroll
        for (int j = 0; j < 4; ++j) key[j] = fkey(p ? -v[j] : v[j]);
        unsigned prefix = 0;
        int gsel = 0;   // count of keys known strictly greater than current prefix path
        for (int pass = 0; pass < 4; ++pass) {
            int shift = 24 - 8 * pass;
            hist[tid] = 0;
            __syncthreads();
            #pragma unroll
            for (int j = 0; j < 4; ++j) {
                bool match = (pass == 0) || ((key[j] >> (shift + 8)) == prefix);
                if (match) atomicAdd(&hist[(key[j] >> shift) & 255], 1);
            }
            __syncthreads();
            if (tid == 0) {
                int need = 64 - gsel;
                int acc = 0, b = 255;
                for (; b >= 0; --b) {
                    int h = hist[b];
                    if (acc + h >= need) break;
                    acc += h;
                }
                chosen_s = b;
                gsel_s = gsel + acc;
            }
            __syncthreads();
            prefix = (prefix << 8) | (unsigned)chosen_s;
            gsel = gsel_s;
        }
        unsigned kstar = prefix;      // exact 64th-largest key
        int need_eq = 64 - gsel;      // equal-key slots to fill (lowest indices first)
        float asum = 0.0f;
        int eqc = 0;
        #pragma unroll
        for (int j = 0; j < 4; ++j) {
            if (key[j] > kstar) asum += agr[4 * tid + j];
            else if (key[j] == kstar) eqc++;
        }
        scan[tid] = eqc;
        __syncthreads();
        for (int o = 1; o < 256; o <<= 1) {
            int val = (tid >= o) ? scan[tid - o] : 0;
            __syncthreads();
            scan[tid] += val;
            __syncthreads();
        }
        int eqr = scan[tid] - eqc;    // exclusive prefix in index order
        #pragma unroll
        for (int j = 0; j < 4; ++j) {
            if (key[j] == kstar) { if (eqr < need_eq) asum += agr[4 * tid + j]; eqr++; }
        }
        red[tid] = asum;
        __syncthreads();
        for (int o = 128; o > 0; o >>= 1) {
            if (tid < o) red[tid] += red[tid + o];
            __syncthreads();
        }
        mres[p] = red[0] * (1.0f / 64.0f);
        __syncthreads();
    }
    if (tid == 0) {
        float r = mres[1] - mres[0] + 0.5f;
        trip[t] = r > 0.0f ? r : 0.0f;
    }
}

__global__ __launch_bounds__(256)
void trip_mean_kernel(const float* __restrict__ trip, float* __restrict__ out)
{
    int tid = threadIdx.x;
    float s = 0.0f;
    for (int i = tid; i < 2048; i += 256) s += trip[i];
    __shared__ float rs[256];
    rs[tid] = s; __syncthreads();
    for (int o = 128; o > 0; o >>= 1) { if (tid < o) rs[tid] += rs[tid + o]; __syncthreads(); }
    if (tid == 0) out[2097152] = rs[0] * (1.0f / 2048.0f);
}

// ============================ launch ============================
extern "C" void kernel_launch(void* const* d_in, const int* in_sizes, int n_in,
                              void* d_out, int out_size, void* d_ws, size_t ws_size,
                              hipStream_t stream)
{
    const float* hidden = (const float*)d_in[0];
    const float* amask  = (const float*)d_in[1];
    const float* ln1g   = (const float*)d_in[2];
    const float* ln1b   = (const float*)d_in[3];
    const float* Wq     = (const float*)d_in[4];
    const float* bq     = (const float*)d_in[5];
    const float* Wk     = (const float*)d_in[6];
    const float* bk     = (const float*)d_in[7];
    const float* Wv     = (const float*)d_in[8];
    const float* bv     = (const float*)d_in[9];
    const float* Wo     = (const float*)d_in[10];
    const float* bo     = (const float*)d_in[11];
    const float* ln2g   = (const float*)d_in[12];
    const float* ln2b   = (const float*)d_in[13];
    const float* W1     = (const float*)d_in[14];
    const float* b1     = (const float*)d_in[15];
    const float* Whash  = (const float*)d_in[16];
    const float* W2     = (const float*)d_in[17];
    const float* b2w    = (const float*)d_in[18];
    float* out = (float*)d_out;
    float* ws  = (float*)d_ws;
    const size_t MB = 1024 * 1024;
    if (ws_size < 20 * MB) return;

    // ---- ws layout (floats), 20 MB ----
    float* xln    = ws;                 // [0,8MB)
    float* qg     = ws + 2097152;       // [8,12MB)
    float* kg     = ws + 3145728;       // [12,16MB)
    float* vg     = ws + 4194304;       // [16,20MB)
    float* attnO  = ws + 2097152;       // [8,16MB) after flash
    float* normed = ws;                 // [0,8MB)
    bf16*  logits = (bf16*)(ws + 4194304); // [16,20MB)
    int*   sids_ws = (int*)ws;          // [0,8KB) after normed dead

    // ---- d_out scratch layout (floats) ----
    float* ctx    = out;
    float* projn  = out;
    float* tanhpt = out + 524288;
    float* tanhpn = out + 786432;
    int*   dints  = (int*)out + 1048576;
    int*   code_n = dints;
    int*   code_t = dints + 65536;
    int*   hist   = dints + 98304;
    int*   score  = dints + 106496;
    int*   shist  = dints + 114688;
    int*   selmeta= dints + 147460;
    int*   sids   = dints + 147464;
    float* trip   = (float*)(dints + 149512);

    // ---- attention (2 head-groups of 8; f32) ----
    ln_kernel<<<2048, 256, 0, stream>>>(hidden, ln1g, ln1b, xln);
    for (int g = 0; g < 2; ++g) {
        const size_t wOff = (size_t)g * 512 * 1024;
        qkv_kernel<<<dim3(8, 32, 3), 256, 0, stream>>>(xln, Wq + wOff, Wk + wOff, Wv + wOff,
                                                       bq + g * 512, bk + g * 512, bv + g * 512,
                                                       qg, kg, vg);
        flash_kernel<<<dim3(64, 8), 256, 0, stream>>>(qg, kg, vg, amask, ctx, g * 8);
    }
    gemm_nt_t<float><<<dim3(16, 32), 256, 0, stream>>>(ctx, 1024, Wo, 1024, nullptr, bo, hidden, attnO, 0, 1024, 0, 2048, 1024, 1024);

    // ---- FFN routing (hash projections stay f64-accumulated: sign-critical) ----
    ln_kernel<<<2048, 256, 0, stream>>>(attnO, ln2g, ln2b, normed);
    gemm_nt_t<double><<<dim3(2, 64), 256, 0, stream>>>(W1, 1024, Whash, 1024, nullptr, nullptr, nullptr, projn, 0, 0, 3, 4096, 128, 1024);
    code_n_kernel<<<256, 256, 0, stream>>>(projn, code_n, hist);
    gemm_nt_t<double><<<dim3(2, 32), 256, 0, stream>>>(normed, 1024, Whash, 1024, nullptr, nullptr, nullptr, tanhpt, 0, 128, 0, 2048, 128, 1024);
    code_t_kernel<<<128, 256, 0, stream>>>(tanhpt, code_t);
    hist_kernel<<<128, 256, 0, stream>>>(code_t, hist);
    score_kernel<<<32, 256, 0, stream>>>(hist, code_n, score, shist);
    select_kernel<<<2, 256, 0, stream>>>(shist, selmeta);
    build_sids_kernel<<<2, 256, 0, stream>>>(score, selmeta, sids);
    tanhpn_kernel<<<1024, 256, 0, stream>>>(projn, sids, tanhpn);

    // ---- logits (bf16, ws; f32 acc), both chunks in one launch ----
    logits_kernel<<<dim3(16, 16, 2), 256, 0, stream>>>(normed, W1, sids, b1, logits);

    // ---- triplet (reads d_out scratch; must precede final writes) ----
    topk_kernel<<<2048, 256, 0, stream>>>(logits, tanhpt, tanhpn, trip);
    trip_mean_kernel<<<1, 256, 0, stream>>>(trip, out);

    // ---- final FFN output (overwrites d_out matrix) ----
    copy_int_kernel<<<8, 256, 0, stream>>>(sids, sids_ws, 2048);
    out_kernel<<<dim3(16, 16, 2), 256, 0, stream>>>(logits, W2, sids_ws, b2w, attnO, out);
}